// Round 16
// baseline (256.769 us; speedup 1.0000x reference)
//
#include <hip/hip_runtime.h>
#include <hip/hip_bf16.h>
#include <math.h>

// Model dims: V=50000, A=1000, E=100, K=256, F=8, B=256, S=512, KS=(2,3,4,5)

typedef __attribute__((ext_vector_type(8))) short short8;
typedef __attribute__((ext_vector_type(4))) short short4v;
typedef __attribute__((ext_vector_type(4))) float f32x4;

__device__ __forceinline__ void gld_lds16(const void* g, void* l) {
  __builtin_amdgcn_global_load_lds(
      (const __attribute__((address_space(1))) unsigned int*)g,
      (__attribute__((address_space(3))) unsigned int*)l, 16, 0, 0);
}

__device__ __forceinline__ short bf16of(float f) {
  union { float f; unsigned u; } x; x.f = f;
  unsigned r = (x.u + 0x7fff + ((x.u >> 16) & 1)) >> 16;   // RNE, matches __float2bfloat16
  return (short)r;
}

// ---------------------------------------------------------------------------
// One grid-stride prep kernel, vec4 (verified R10): emb_bf [50001][128]
// (row 50000 = zeros, cols 100..127 = 0), Wc [1024][640] + cb, 4 epilogue
// weights (bf16, zero-padded), ids_pad [131080] (tail -> 50000 = zero row).
#define O1 6400128   // emb_bf
#define O2 7055488   // Wc
#define O3 8104064   // wt_sc
#define O4 10201216  // wt_fic
#define O5 12298368  // wt_fus
#define O6 13346944  // wt_out
#define OT 13478024
__global__ __launch_bounds__(256) void prep_all(
    const int* __restrict__ text_ids, const float* __restrict__ emb,
    const float* __restrict__ w2, const float* __restrict__ w3,
    const float* __restrict__ w4, const float* __restrict__ w5,
    const float* __restrict__ b2, const float* __restrict__ b3,
    const float* __restrict__ b4, const float* __restrict__ b5,
    const float* __restrict__ sc_w, const float* __restrict__ fic_w,
    const float* __restrict__ fus_w, const float* __restrict__ out_w,
    __hip_bfloat16* __restrict__ emb_bf, __hip_bfloat16* __restrict__ Wc,
    float* __restrict__ cb, __hip_bfloat16* __restrict__ wt_sc,
    __hip_bfloat16* __restrict__ wt_fic, __hip_bfloat16* __restrict__ wt_fus,
    __hip_bfloat16* __restrict__ wt_out, int* __restrict__ ids_pad) {
  for (int v = blockIdx.x * 256 + threadIdx.x; v < OT / 4;
       v += gridDim.x * 256) {
    const int idx = v * 4;
    if (idx < O1) {                       // emb_bf
      const int row = idx >> 7, e = idx & 127;
      float4 f = make_float4(0.f, 0.f, 0.f, 0.f);
      if (row < 50000 && e < 100)          // e in {0,4,..,96}: e+3<=99 valid
        f = *(const float4*)(emb + row * 100 + e);
      *(short4v*)(emb_bf + idx) =
          (short4v){bf16of(f.x), bf16of(f.y), bf16of(f.z), bf16of(f.w)};
    } else if (idx < O2) {                // Wc + cb
      const int t = idx - O1;
      const int n = t / 640, k = t % 640;  // 640%4==0 -> same n, same dh
      const int h = 2 + (n >> 8), kc = n & 255;
      const int dh = k >> 7, e = k & 127;
      const float* w = (h == 2) ? w2 : (h == 3) ? w3 : (h == 4) ? w4 : w5;
      short4v o;
#pragma unroll
      for (int i = 0; i < 4; ++i)
        o[i] = (dh < h && e + i < 100) ? bf16of(w[(kc * 100 + e + i) * h + dh])
                                       : (short)0;
      *(short4v*)(Wc + t) = o;
      if (k == 0) {
        const float* bb = (h == 2) ? b2 : (h == 3) ? b3 : (h == 4) ? b4 : b5;
        cb[n] = bb[kc];
      }
    } else if (idx < O3) {                // sc: [1000][1024] -> [1024][1024]
      const int t = idx - O2;
      const int n = t >> 10, k = t & 1023;
      float4 f = make_float4(0.f, 0.f, 0.f, 0.f);
      if (n < 1000) f = *(const float4*)(sc_w + n * 1024 + k);
      *(short4v*)(wt_sc + t) =
          (short4v){bf16of(f.x), bf16of(f.y), bf16of(f.z), bf16of(f.w)};
    } else if (idx < O4) {                // fic: [1000][2000] -> [1024][2048]
      const int t = idx - O3;
      const int n = t >> 11, k = t & 2047;
      float4 f = make_float4(0.f, 0.f, 0.f, 0.f);
      if (n < 1000 && k < 2000) f = *(const float4*)(fic_w + n * 2000 + k);
      *(short4v*)(wt_fic + t) =
          (short4v){bf16of(f.x), bf16of(f.y), bf16of(f.z), bf16of(f.w)};
    } else if (idx < O5) {                // fus: [1000][2000] -> [1024][2048]
      const int t = idx - O4;
      const int n = t >> 11, k = t & 2047;
      float4 f = make_float4(0.f, 0.f, 0.f, 0.f);
      if (n < 1000 && k < 2000) f = *(const float4*)(fus_w + n * 2000 + k);
      *(short4v*)(wt_fus + t) =
          (short4v){bf16of(f.x), bf16of(f.y), bf16of(f.z), bf16of(f.w)};
    } else if (idx < O6) {                // out: [1000][1000] -> [1024][1024]
      const int t = idx - O5;
      const int n = t >> 10, k = t & 1023;
      float4 f = make_float4(0.f, 0.f, 0.f, 0.f);
      if (n < 1000 && k < 1000) f = *(const float4*)(out_w + n * 1000 + k);
      *(short4v*)(wt_out + t) =
          (short4v){bf16of(f.x), bf16of(f.y), bf16of(f.z), bf16of(f.w)};
    } else {                              // ids_pad
      const int t = idx - O6;
      if (t + 3 < 131072) {
        *(int4*)(ids_pad + t) = *(const int4*)(text_ids + t);
      } else {
#pragma unroll
        for (int i = 0; i < 4; ++i)
          ids_pad[t + i] = (t + i < 131072) ? text_ids[t + i] : 50000;
      }
    }
  }
}

// ---------------------------------------------------------------------------
// Implicit-GEMM conv + bias + relu + maxpool; persistent per-(batch, nb) block.
// R10-VERIFIED 256x256 version (169.9-170.3 us): one block = batch b x N-tile
// nb, 8 waves (2Mx4N, wave tile 128x64 -> 0.375 LDS-reads/MFMA), BK=64, LDS
// dbuf 128 KB (1 blk/CU); 2 M-subtiles through ONE continuous counted-
// vmcnt(8) pipeline; max-fold at subtile boundary (exactly associative);
// in-block maxpool -> direct stores; emits e_bf. [R15: fp8 failed accuracy
// (0.906 > 0.8); R11/R14 128^2 variant is 4-5 us slower (worse read ratio).]
__global__ __launch_bounds__(512, 2) void conv_mfma(const __hip_bfloat16* __restrict__ Eb_,
                                                    const int* __restrict__ ids_pad,
                                                    const __hip_bfloat16* __restrict__ Wc_,
                                                    const float* __restrict__ cb,
                                                    float* __restrict__ e_out,
                                                    __hip_bfloat16* __restrict__ e_bf) {
  __shared__ __align__(16) short As[2][256 * 64];  // 64 KB
  __shared__ __align__(16) short Bs[2][256 * 64];  // 64 KB
  __shared__ int ids_s[520];                       // 516 used
  __shared__ float pm_s[8][64];
  const int g = blockIdx.x;
  const int xcd = g & 7, i = g >> 3;
  const int nb = 3 - (i & 3);            // long (nb=3) blocks dispatch first
  const int b = ((i >> 2) << 3) | xcd;   // 0..255; siblings share xcd
  const int N0 = nb << 8;
  const int nt = (2 + nb) * 2;           // K-steps of 64 per subtile: 4/6/8/10
  const int NS = nt * 2;                 // total steps (2 M-subtiles)
  const int tid = threadIdx.x;
  const int lane = tid & 63;
  const int wid = tid >> 6;
  const int wr = wid >> 2, wc = wid & 3;  // 2x4 wave grid; wave tile 128x64
  const short* Eb = (const short*)Eb_;
  const short* Wc = (const short*)Wc_;

  ids_s[tid] = ids_pad[b * 512 + tid];                           // 0..511
  if (tid < 4) ids_s[512 + tid] = ids_pad[b * 512 + 512 + tid];  // 512..515
  __syncthreads();

  f32x4 acc[8][4];
#pragma unroll
  for (int ii = 0; ii < 8; ++ii)
#pragma unroll
    for (int jj = 0; jj < 4; ++jj) acc[ii][jj] = (f32x4){0.f, 0.f, 0.f, 0.f};
  float pm[4] = {-3.0e38f, -3.0e38f, -3.0e38f, -3.0e38f};

  // Stage one BK=64 slab of A and B. LDS chunk (row,cs) holds global col
  // chunk (cs ^ (row&7)) -- involution pair with the swizzled read.
  auto STAGE = [&](int buf, int step) {
    const int sub = (step >= nt);
    const int ms = sub ? 256 : 0;
    const int k0 = (step - (sub ? nt : 0)) << 6;
    const int dh = k0 >> 7, e0 = k0 & 127;   // 64-col slab lies in one dh
#pragma unroll
    for (int ii = 0; ii < 4; ++ii) {
      const int c = tid + (ii << 9);         // 0..2047
      const int row = c >> 3, cs = c & 7;
      const int scs = cs ^ (row & 7);
      const int id = ids_s[ms + row + dh];   // lgkm read; keeps vmcnt pure
      gld_lds16(Eb + ((long)id << 7) + e0 + scs * 8, &As[buf][c * 8]);
      gld_lds16(Wc + (long)(N0 + row) * 640 + k0 + scs * 8, &Bs[buf][c * 8]);
    }
  };

  STAGE(0, 0);
  for (int t = 0; t < NS; ++t) {
    if (t + 1 < NS) {
      STAGE((t + 1) & 1, t + 1);
      asm volatile("s_waitcnt vmcnt(8)" ::: "memory");   // stage(t) done only
    } else {
      asm volatile("s_waitcnt vmcnt(0)" ::: "memory");
    }
    __builtin_amdgcn_s_barrier();          // A: stage(t) visible to all waves
    const short* Ab = As[t & 1];
    const short* Bb = Bs[t & 1];
#pragma unroll
    for (int ks = 0; ks < 2; ++ks) {
      const int csq = ks * 4 + (lane >> 4);
      short8 av[8], bv[4];
#pragma unroll
      for (int mf = 0; mf < 8; ++mf) {
        const int row = wr * 128 + mf * 16 + (lane & 15);
        av[mf] = *(const short8*)&Ab[row * 64 + (csq ^ (row & 7)) * 8];
      }
#pragma unroll
      for (int nf = 0; nf < 4; ++nf) {
        const int row = wc * 64 + nf * 16 + (lane & 15);
        bv[nf] = *(const short8*)&Bb[row * 64 + (csq ^ (row & 7)) * 8];
      }
#pragma unroll
      for (int mf = 0; mf < 8; ++mf)
#pragma unroll
        for (int nf = 0; nf < 4; ++nf)
          acc[mf][nf] = __builtin_amdgcn_mfma_f32_16x16x32_bf16(av[mf], bv[nf], acc[mf][nf], 0, 0, 0);
    }
    // Subtile-boundary fold: max is exactly associative; reset acc.
    if (t == nt - 1 || t == NS - 1) {
      const bool masked = (t == NS - 1);   // subtile 1: t_global = 256 + tloc
#pragma unroll
      for (int nf = 0; nf < 4; ++nf) {
#pragma unroll
        for (int mf = 0; mf < 8; ++mf) {
          const int tloc = wr * 128 + mf * 16 + (lane >> 4) * 4;
#pragma unroll
          for (int r = 0; r < 4; ++r) {
            if (!masked || (tloc + r <= 254 - nb))
              pm[nf] = fmaxf(pm[nf], acc[mf][nf][r]);
            acc[mf][nf][r] = 0.f;
          }
        }
      }
    }
    asm volatile("s_waitcnt lgkmcnt(0)" ::: "memory");
    __builtin_amdgcn_s_barrier();          // B: reads done before buf reuse
  }

  // Cross-wr combine in LDS, then bias+relu+store (no atomics).
#pragma unroll
  for (int nf = 0; nf < 4; ++nf) {
    float p = pm[nf];
    p = fmaxf(p, __shfl_xor(p, 16, 64));
    p = fmaxf(p, __shfl_xor(p, 32, 64));
    if ((lane >> 4) == 0) pm_s[wid][nf * 16 + (lane & 15)] = p;
  }
  __syncthreads();
  if (tid < 256) {
    const int wcx = tid >> 6, off = tid & 63;
    const int n = N0 + wcx * 64 + off;
    const float v0 = fmaxf(pm_s[wcx][off], pm_s[4 + wcx][off]);
    const float v = fmaxf(v0 + cb[n], 0.f);  // relu(max+bias) == max(relu)
    e_out[b * 1024 + n] = v;
    e_bf[b * 1024 + n] = __float2bfloat16(v);
  }
}

// ---------------------------------------------------------------------------
// 64x128-tile epilogue GEMM body (4 waves 2x2, wave tile 32x64, BK=64,
// swizzled LDS, counted vmcnt(6) depth-1 pipeline).
template<int ACT, int OUTBF>
__device__ __forceinline__ void gemm64_body(const short* __restrict__ A, int lda,
                                            const short* __restrict__ W, int ldw,
                                            const float* __restrict__ bias,
                                            void* __restrict__ Cv, int ldc,
                                            int N, int K, int cofs, int M0, int N0,
                                            short* As0, short* As1,
                                            short* Bs0, short* Bs1) {
  const int tid = threadIdx.x, lane = tid & 63;
  const int wid = tid >> 6;
  const int wr = wid >> 1, wc = wid & 1;
  short* Asb[2] = {As0, As1};
  short* Bsb[2] = {Bs0, Bs1};

  f32x4 acc[2][4];
#pragma unroll
  for (int i = 0; i < 2; ++i)
#pragma unroll
    for (int j = 0; j < 4; ++j) acc[i][j] = (f32x4){0.f, 0.f, 0.f, 0.f};

  auto STAGE = [&](int buf, int k0) {
#pragma unroll
    for (int i = 0; i < 2; ++i) {          // A: 512 chunks (64 rows)
      const int c = tid + (i << 8);
      const int row = c >> 3, cs = c & 7;
      const int scs = cs ^ (row & 7);
      gld_lds16(A + (long)(M0 + row) * lda + k0 + scs * 8, &Asb[buf][c * 8]);
    }
#pragma unroll
    for (int i = 0; i < 4; ++i) {          // B: 1024 chunks (128 rows)
      const int c = tid + (i << 8);
      const int row = c >> 3, cs = c & 7;
      const int scs = cs ^ (row & 7);
      gld_lds16(W + (long)(N0 + row) * ldw + k0 + scs * 8, &Bsb[buf][c * 8]);
    }
  };

  const int nt = K >> 6;
  STAGE(0, 0);
  for (int t = 0; t < nt; ++t) {
    if (t + 1 < nt) {
      STAGE((t + 1) & 1, (t + 1) << 6);
      asm volatile("s_waitcnt vmcnt(6)" ::: "memory");
    } else {
      asm volatile("s_waitcnt vmcnt(0)" ::: "memory");
    }
    __builtin_amdgcn_s_barrier();
    const short* Ab = Asb[t & 1];
    const short* Bb = Bsb[t & 1];
#pragma unroll
    for (int ks = 0; ks < 2; ++ks) {
      const int csq = ks * 4 + (lane >> 4);
      short8 av[2], bv[4];
#pragma unroll
      for (int mf = 0; mf < 2; ++mf) {
        const int row = wr * 32 + mf * 16 + (lane & 15);
        av[mf] = *(const short8*)&Ab[row * 64 + (csq ^ (row & 7)) * 8];
      }
#pragma unroll
      for (int nf = 0; nf < 4; ++nf) {
        const int row = wc * 64 + nf * 16 + (lane & 15);
        bv[nf] = *(const short8*)&Bb[row * 64 + (csq ^ (row & 7)) * 8];
      }
#pragma unroll
      for (int mf = 0; mf < 2; ++mf)
#pragma unroll
        for (int nf = 0; nf < 4; ++nf)
          acc[mf][nf] = __builtin_amdgcn_mfma_f32_16x16x32_bf16(av[mf], bv[nf], acc[mf][nf], 0, 0, 0);
    }
    asm volatile("s_waitcnt lgkmcnt(0)" ::: "memory");
    __builtin_amdgcn_s_barrier();
  }

#pragma unroll
  for (int nf = 0; nf < 4; ++nf) {
    const int n = N0 + wc * 64 + nf * 16 + (lane & 15);
    const float bv = (n < N) ? bias[n] : 0.f;
#pragma unroll
    for (int mf = 0; mf < 2; ++mf) {
      const int m = M0 + wr * 32 + mf * 16 + (lane >> 4) * 4;
#pragma unroll
      for (int r = 0; r < 4; ++r) {
        float v = acc[mf][nf][r] + bv;
        if (ACT) v = tanhf(v);
        if (n < N) {
          if (OUTBF)
            ((__hip_bfloat16*)Cv)[(long)(m + r) * ldc + cofs + n] = __float2bfloat16(v);
          else
            ((float*)Cv)[(long)(m + r) * ldc + cofs + n] = v;
        }
      }
    }
  }
}

template<int ACT, int OUTBF>
__global__ __launch_bounds__(256) void gemm64(const __hip_bfloat16* __restrict__ A_,
                                              int lda,
                                              const __hip_bfloat16* __restrict__ W_,
                                              int ldw,
                                              const float* __restrict__ bias,
                                              void* __restrict__ Cv, int ldc,
                                              int N, int K) {
  __shared__ __align__(16) short As[2][64 * 64];   // 16 KB
  __shared__ __align__(16) short Bs[2][128 * 64];  // 32 KB
  gemm64_body<ACT, OUTBF>((const short*)A_, lda, (const short*)W_, ldw, bias,
                          Cv, ldc, N, K, 0, blockIdx.y << 6, blockIdx.x << 7,
                          As[0], As[1], Bs[0], Bs[1]);
}

// Fused u_sc (z=0, linear) + u_fic (z=1, tanh) -> cat_sc_bf[:, z*1000 + n]
__global__ __launch_bounds__(256) void gemm64_sc_fic(
    const __hip_bfloat16* __restrict__ e_bf,
    const __hip_bfloat16* __restrict__ cat_mm_bf,
    const __hip_bfloat16* __restrict__ wt_sc,
    const __hip_bfloat16* __restrict__ wt_fic,
    const float* __restrict__ sc_b, const float* __restrict__ fic_b,
    __hip_bfloat16* __restrict__ cat_sc) {
  __shared__ __align__(16) short As[2][64 * 64];
  __shared__ __align__(16) short Bs[2][128 * 64];
  const int z = blockIdx.z;
  if (z == 0)
    gemm64_body<0, 1>((const short*)e_bf, 1024, (const short*)wt_sc, 1024, sc_b,
                      cat_sc, 2048, 1000, 1024, 0, blockIdx.y << 6,
                      blockIdx.x << 7, As[0], As[1], Bs[0], Bs[1]);
  else
    gemm64_body<1, 1>((const short*)cat_mm_bf, 2048, (const short*)wt_fic, 2048,
                      fic_b, cat_sc, 2048, 1000, 2048, 1000, blockIdx.y << 6,
                      blockIdx.x << 7, As[0], As[1], Bs[0], Bs[1]);
}

// ---------------------------------------------------------------------------
// Fused heads: per block b -- u_t (wave reduce), s1, then cat_mm_bf[b,:1000]=
// u_mm, [1000:2000]=u_mlp (s2 recomputed per api column), [2000:2048]=0.
__global__ __launch_bounds__(256) void k_heads(const float* __restrict__ e_buf,
                                               const float* __restrict__ W,
                                               const float* __restrict__ bias,
                                               const float* __restrict__ api,
                                               const float* __restrict__ mlp_w1,
                                               const float* __restrict__ mlp_b1,
                                               const float* __restrict__ mlp_w2,
                                               const float* __restrict__ mlp_b2,
                                               __hip_bfloat16* __restrict__ cat) {
  const int b = blockIdx.x, tid = threadIdx.x;
  float4 a = *(const float4*)(e_buf + b * 1024 + tid * 4);
  float acc[8];
#pragma unroll
  for (int f = 0; f < 8; ++f) {
    float4 w = *(const float4*)(W + f * 1024 + tid * 4);
    acc[f] = a.x * w.x + a.y * w.y + a.z * w.z + a.w * w.w;
  }
#pragma unroll
  for (int f = 0; f < 8; ++f)
    for (int off = 32; off; off >>= 1) acc[f] += __shfl_down(acc[f], off);
  __shared__ float red[4][8];
  __shared__ float ut_s[8];
  __shared__ float s1_s;
  if ((tid & 63) == 0) {
#pragma unroll
    for (int f = 0; f < 8; ++f) red[tid >> 6][f] = acc[f];
  }
  __syncthreads();
  if (tid == 0) {
    float s = 0.f;
#pragma unroll
    for (int f = 0; f < 8; ++f)
      ut_s[f] = red[0][f] + red[1][f] + red[2][f] + red[3][f] + bias[f];
#pragma unroll
    for (int f = 0; f < 8; ++f) {
      float t1 = 0.f;
#pragma unroll
      for (int fp = 0; fp < 8; ++fp) t1 += mlp_w1[f * 16 + fp] * ut_s[fp];
      s += t1 * mlp_w2[f];
    }
    s1_s = s;
  }
  __syncthreads();
  const float s1v = s1_s;
#pragma unroll
  for (int i = 0; i < 4; ++i) {
    const int j = tid + i * 256;           // 0..1023
    if (j < 1000) {
      float ap[8];
#pragma unroll
      for (int fp = 0; fp < 8; ++fp) ap[fp] = api[fp * 1000 + j];
      float umm = 0.f;
#pragma unroll
      for (int f = 0; f < 8; ++f) umm += ut_s[f] * ap[f];
      float s2 = mlp_b2[0];
#pragma unroll
      for (int f = 0; f < 8; ++f) {
        float t2 = mlp_b1[f];
#pragma unroll
        for (int fp = 0; fp < 8; ++fp) t2 += mlp_w1[f * 16 + 8 + fp] * ap[fp];
        s2 += t2 * mlp_w2[f];
      }
      cat[b * 2048 + j] = __float2bfloat16(umm);
      cat[b * 2048 + 1000 + j] = __float2bfloat16(tanhf(s1v + s2));
    }
  }
  if (tid < 48) cat[b * 2048 + 2000 + tid] = __float2bfloat16(0.f);
}

// ---------------------------------------------------------------------------
// FALLBACK (round-0 f32 path) — used only if ws_size is too small.
__global__ __launch_bounds__(256) void transpose_w(const float* __restrict__ w,
                                                   float* __restrict__ wt, int EH) {
  int idx = blockIdx.x * 256 + threadIdx.x;
  if (idx >= 256 * EH) return;
  int k = idx / EH, r = idx % EH;
  wt[r * 256 + k] = w[idx];
}

template<int H>
__global__ __launch_bounds__(256) void conv_pool(const int* __restrict__ ids,
                                                 const float* __restrict__ emb,
                                                 const float* __restrict__ wt,
                                                 const float* __restrict__ cbias,
                                                 float* __restrict__ e_out,
                                                 int hidx) {
  const int b = blockIdx.y;
  const int t0 = blockIdx.x * 32;
  const int L = 512 - H + 1;
  __shared__ float4 xs4[100][10];
  float* xs = (float*)xs4;
  const int tid = threadIdx.x;
  const int WIN = 32 + H - 1;
  for (int idx = tid; idx < WIN * 25; idx += 256) {
    int p = idx / 25, c = idx % 25;
    int s = t0 + p;
    float4 v = make_float4(0.f, 0.f, 0.f, 0.f);
    if (s < 512) {
      int id = ids[b * 512 + s];
      v = *(const float4*)(emb + (long)id * 100 + c * 4);
    }
    xs[(4 * c + 0) * 40 + p] = v.x;
    xs[(4 * c + 1) * 40 + p] = v.y;
    xs[(4 * c + 2) * 40 + p] = v.z;
    xs[(4 * c + 3) * 40 + p] = v.w;
  }
  __syncthreads();
  const int k = tid;
  float acc[32];
#pragma unroll
  for (int t = 0; t < 32; ++t) acc[t] = 0.f;
  const float* wk = wt + k;
  for (int e = 0; e < 100; ++e) {
    float win[36];
#pragma unroll
    for (int i = 0; i < 9; ++i)
      *(float4*)&win[i * 4] = *(const float4*)&xs[e * 40 + i * 4];
    float wr[H];
#pragma unroll
    for (int dh = 0; dh < H; ++dh) wr[dh] = wk[(e * H + dh) * 256];
#pragma unroll
    for (int t = 0; t < 32; ++t) {
      float s = acc[t];
#pragma unroll
      for (int dh = 0; dh < H; ++dh) s = fmaf(wr[dh], win[t + dh], s);
      acc[t] = s;
    }
  }
  const float bk = cbias[k];
  float m = 0.f;
#pragma unroll
  for (int t = 0; t < 32; ++t) {
    if (t0 + t < L) m = fmaxf(m, fmaxf(acc[t] + bk, 0.f));
  }
  atomicMax((int*)&e_out[b * 1024 + hidx * 256 + k], __float_as_int(m));
}

__global__ __launch_bounds__(256) void k_ut_s1(const float* __restrict__ e_buf,
                                               const float* __restrict__ W,
                                               const float* __restrict__ bias,
                                               const float* __restrict__ mlp_w1,
                                               const float* __restrict__ mlp_w2,
                                               float* __restrict__ u_t,
                                               float* __restrict__ s1) {
  const int b = blockIdx.x, tid = threadIdx.x;
  float4 a = *(const float4*)(e_buf + b * 1024 + tid * 4);
  float acc[8];
#pragma unroll
  for (int f = 0; f < 8; ++f) {
    float4 w = *(const float4*)(W + f * 1024 + tid * 4);
    acc[f] = a.x * w.x + a.y * w.y + a.z * w.z + a.w * w.w;
  }
#pragma unroll
  for (int f = 0; f < 8; ++f)
    for (int off = 32; off; off >>= 1) acc[f] += __shfl_down(acc[f], off);
  __shared__ float red[4][8];
  if ((tid & 63) == 0) {
#pragma unroll
    for (int f = 0; f < 8; ++f) red[tid >> 6][f] = acc[f];
  }
  __syncthreads();
  if (tid == 0) {
    float ut[8];
#pragma unroll
    for (int f = 0; f < 8; ++f) {
      ut[f] = red[0][f] + red[1][f] + red[2][f] + red[3][f] + bias[f];
      u_t[b * 8 + f] = ut[f];
    }
    float s = 0.f;
#pragma unroll
    for (int f = 0; f < 8; ++f) {
      float t1 = 0.f;
#pragma unroll
      for (int fp = 0; fp < 8; ++fp) t1 += mlp_w1[f * 16 + fp] * ut[fp];
      s += t1 * mlp_w2[f];
    }
    s1[b] = s;
  }
}

__global__ __launch_bounds__(256) void k_s2(const float* __restrict__ api,
                                            const float* __restrict__ mlp_w1,
                                            const float* __restrict__ mlp_b1,
                                            const float* __restrict__ mlp_w2,
                                            const float* __restrict__ mlp_b2,
                                            float* __restrict__ s2) {
  int a = blockIdx.x * 256 + threadIdx.x;
  if (a >= 1000) return;
  float ap[8];
#pragma unroll
  for (int fp = 0; fp < 8; ++fp) ap[fp] = api[fp * 1000 + a];
  float s = mlp_b2[0];
#pragma unroll
  for (int f = 0; f < 8; ++f) {
    float t2 = mlp_b1[f];
#pragma unroll
    for (int fp = 0; fp < 8; ++fp) t2 += mlp_w1[f * 16 + 8 + fp] * ap[fp];
    s += t2 * mlp_w2[f];
  }
  s2[a] = s;
}

__global__ __launch_bounds__(256) void k_cat_f32(const float* __restrict__ u_t,
                                                 const float* __restrict__ api,
                                                 const float* __restrict__ s1,
                                                 const float* __restrict__ s2,
                                                 float* __restrict__ cat_mm) {
  int j = blockIdx.x * 256 + threadIdx.x;
  int b = blockIdx.y;
  if (j >= 2000) return;
  if (j < 1000) {
    float v = 0.f;
#pragma unroll
    for (int f = 0; f < 8; ++f) v += u_t[b * 8 + f] * api[f * 1000 + j];
    cat_mm[b * 2000 + j] = v;
  } else {
    cat_mm[b * 2000 + j] = tanhf(s1[b] + s2[j - 1000]);
  }
}

template<int ACT>
__global__ __launch_bounds__(256) void gemm_tn(const float* __restrict__ A, int lda,
                                               const float* __restrict__ W, int ldw,
                                               const float* __restrict__ bias,
                                               float* __restrict__ C, int ldc,
                                               int M, int N, int K) {
  __shared__ float As[8][33];
  __shared__ float Ws[8][33];
  const int n0 = blockIdx.x * 32, m0 = blockIdx.y * 32;
  const int tid = threadIdx.x;
  const int tx = tid % 16, ty = tid / 16;
  const int ms = tid / 8, ks = tid % 8;
  float acc[2][2] = {{0.f, 0.f}, {0.f, 0.f}};
  for (int k0 = 0; k0 < K; k0 += 8) {
    As[ks][ms] = A[(m0 + ms) * lda + k0 + ks];
    int n = n0 + ms;
    Ws[ks][ms] = (n < N) ? W[n * ldw + k0 + ks] : 0.f;
    __syncthreads();
#pragma unroll
    for (int kk = 0; kk < 8; ++kk) {
      float a0 = As[kk][ty], a1 = As[kk][ty + 16];
      float w0 = Ws[kk][tx], w1 = Ws[kk][tx + 16];
      acc[0][0] = fmaf(a0, w0, acc[0][0]);
      acc[0][1] = fmaf(a0, w1, acc[0][1]);
      acc[1][0] = fmaf(a1, w0, acc[1][0]);
      acc[1][1] = fmaf(a1, w1, acc[1][1]);
    }
    __syncthreads();
  }
#pragma unroll
  for (int i = 0; i < 2; ++i)
#pragma unroll
    for (int j = 0; j < 2; ++j) {
      int m = m0 + ty + 16 * i, n = n0 + tx + 16 * j;
      if (n < N) {
        float v = acc[i][j] + bias[n];
        if (ACT) v = tanhf(v);
        C[m * ldc + n] = v;
      }
    }
}

// ---------------------------------------------------------------------------
extern "C" void kernel_launch(void* const* d_in, const int* in_sizes, int n_in,
                              void* d_out, int out_size, void* d_ws, size_t ws_size,
                              hipStream_t stream) {
  const int*   text_ids  = (const int*)d_in[0];
  const float* emb       = (const float*)d_in[1];
  const float* cw2       = (const float*)d_in[2];
  const float* cb2       = (const float*)d_in[3];
  const float* cw3       = (const float*)d_in[4];
  const float* cb3       = (const float*)d_in[5];
  const float* cw4       = (const float*)d_in[6];
  const float* cb4       = (const float*)d_in[7];
  const float* cw5       = (const float*)d_in[8];
  const float* cb5       = (const float*)d_in[9];
  const float* sc_w      = (const float*)d_in[10];
  const float* sc_b      = (const float*)d_in[11];
  const float* fic_fc_w  = (const float*)d_in[12];
  const float* fic_fc_b  = (const float*)d_in[13];
  const float* api       = (const float*)d_in[14];
  const float* mlp_w1    = (const float*)d_in[15];
  const float* mlp_b1    = (const float*)d_in[16];
  const float* mlp_w2    = (const float*)d_in[17];
  const float* mlp_b2    = (const float*)d_in[18];
  const float* fic_fcl_w = (const float*)d_in[19];
  const float* fic_fcl_b = (const float*)d_in[20];
  const float* fusion_w  = (const float*)d_in[21];
  const float* fusion_b  = (const float*)d_in[22];
  const float* out_w     = (const float*)d_in[23];
  const float* out_b     = (const float*)d_in[24];

  float* ws = (float*)d_ws;
  float* e_buf = ws;                       // 262144 f32
  float* cbias = e_buf + 262144;           // 1024
  // bf16 region (offset 263168*4 B, 16-aligned)
  __hip_bfloat16* bfb       = (__hip_bfloat16*)(cbias + 1024);
  __hip_bfloat16* e_bf      = bfb;                  // 262144 (256x1024)
  __hip_bfloat16* cat_mm_bf = e_bf + 262144;        // 524288 (256x2048)
  __hip_bfloat16* cat_sc_bf = cat_mm_bf + 524288;   // 524288 (256x2048)
  __hip_bfloat16* u_mmf_bf  = cat_sc_bf + 524288;   // 262144 (256x1024)
  __hip_bfloat16* emb_bf    = u_mmf_bf + 262144;    // 6400128 (50001x128)
  __hip_bfloat16* Wc        = emb_bf + 6400128;     // 655360
  __hip_bfloat16* wt_sc     = Wc + 655360;          // 1048576
  __hip_bfloat16* wt_fic    = wt_sc + 1048576;      // 2097152
  __hip_bfloat16* wt_fus    = wt_fic + 2097152;     // 2097152
  __hip_bfloat16* wt_out    = wt_fus + 2097152;     // 1048576
  int* ids_pad = (int*)(wt_out + 1048576);          // 131080 ints
  const size_t need_fast =
      263168UL * 4 + 14919808UL * 2 + 131080UL * 4;  // ~31.4 MB

  if (ws_size >= need_fast) {
    prep_all<<<4096, 256, 0, stream>>>(text_ids, emb, cw2, cw3, cw4, cw5,
                                       cb2, cb3, cb4, cb5, sc_w, fic_fcl_w,
                                       fusion_w, out_w, emb_bf, Wc, cbias,
                                       wt_sc, wt_fic, wt_fus, wt_out, ids_pad);
    conv_mfma<<<1024, 512, 0, stream>>>(emb_bf, ids_pad, Wc, cbias, e_buf, e_bf);
    k_heads<<<256, 256, 0, stream>>>(e_buf, fic_fc_w, fic_fc_b, api, mlp_w1,
                                     mlp_b1, mlp_w2, mlp_b2, cat_mm_bf);
    gemm64_sc_fic<<<dim3(8, 4, 2), 256, 0, stream>>>(e_bf, cat_mm_bf, wt_sc,
                                                     wt_fic, sc_b, fic_fcl_b,
                                                     cat_sc_bf);
    gemm64<0, 1><<<dim3(8, 4), 256, 0, stream>>>(cat_sc_bf, 2048, wt_fus, 2048,
                                                 fusion_b, u_mmf_bf, 1024,
                                                 1000, 2048);
    gemm64<0, 0><<<dim3(8, 4), 256, 0, stream>>>(u_mmf_bf, 1024, wt_out, 1024,
                                                 out_b, d_out, 1000, 1000, 1024);
  } else {
    // f32 fallback (round-0 verified path) — needs zeroed e_buf for atomicMax
    hipMemsetAsync(e_buf, 0, 262144 * sizeof(float), stream);
    float* u_t    = (float*)bfb;            // 2048
    float* s1     = u_t + 2048;             // 256
    float* s2     = s1 + 256;               // 1024
    float* cat_mm = s2 + 1024;              // 512000
    float* cat_sc = cat_mm + 512000;        // 512000
    float* u_mmf  = cat_sc + 512000;        // 256000
    float* wt     = u_mmf + 256000;         // 358400
    transpose_w<<<200, 256, 0, stream>>>(cw2, wt + 0,      200);
    transpose_w<<<300, 256, 0, stream>>>(cw3, wt + 51200,  300);
    transpose_w<<<400, 256, 0, stream>>>(cw4, wt + 128000, 400);
    transpose_w<<<500, 256, 0, stream>>>(cw5, wt + 230400, 500);
    conv_pool<2><<<dim3(16, 256), 256, 0, stream>>>(text_ids, emb, wt + 0,      cb2, e_buf, 0);
    conv_pool<3><<<dim3(16, 256), 256, 0, stream>>>(text_ids, emb, wt + 51200,  cb3, e_buf, 1);
    conv_pool<4><<<dim3(16, 256), 256, 0, stream>>>(text_ids, emb, wt + 128000, cb4, e_buf, 2);
    conv_pool<5><<<dim3(16, 256), 256, 0, stream>>>(text_ids, emb, wt + 230400, cb5, e_buf, 3);
    k_ut_s1<<<256, 256, 0, stream>>>(e_buf, fic_fc_w, fic_fc_b, mlp_w1, mlp_w2, u_t, s1);
    k_s2<<<4, 256, 0, stream>>>(api, mlp_w1, mlp_b1, mlp_w2, mlp_b2, s2);
    k_cat_f32<<<dim3(8, 256), 256, 0, stream>>>(u_t, api, s1, s2, cat_mm);
    gemm_tn<0><<<dim3(32, 8), 256, 0, stream>>>(e_buf, 1024, sc_w, 1024, sc_b,
                                                cat_sc, 2000, 256, 1000, 1024);
    gemm_tn<1><<<dim3(32, 8), 256, 0, stream>>>(cat_mm, 2000, fic_fcl_w, 2000, fic_fcl_b,
                                                cat_sc + 1000, 2000, 256, 1000, 2000);
    gemm_tn<0><<<dim3(32, 8), 256, 0, stream>>>(cat_sc, 2000, fusion_w, 2000, fusion_b,
                                                u_mmf, 1000, 256, 1000, 2000);
    gemm_tn<0><<<dim3(32, 8), 256, 0, stream>>>(u_mmf, 1000, out_w, 1000, out_b,
                                                (float*)d_out, 1000, 256, 1000, 1000);
  }
}

// Round 17
// 256.689 us; speedup vs baseline: 1.0003x; 1.0003x over previous
//
#include <hip/hip_runtime.h>
#include <hip/hip_bf16.h>
#include <math.h>

// Model dims: V=50000, A=1000, E=100, K=256, F=8, B=256, S=512, KS=(2,3,4,5)

typedef __attribute__((ext_vector_type(8))) short short8;
typedef __attribute__((ext_vector_type(4))) short short4v;
typedef __attribute__((ext_vector_type(4))) float f32x4;

__device__ __forceinline__ void gld_lds16(const void* g, void* l) {
  __builtin_amdgcn_global_load_lds(
      (const __attribute__((address_space(1))) unsigned int*)g,
      (__attribute__((address_space(3))) unsigned int*)l, 16, 0, 0);
}

__device__ __forceinline__ short bf16of(float f) {
  union { float f; unsigned u; } x; x.f = f;
  unsigned r = (x.u + 0x7fff + ((x.u >> 16) & 1)) >> 16;   // RNE, matches __float2bfloat16
  return (short)r;
}

// ---------------------------------------------------------------------------
// One grid-stride prep kernel, vec4 (verified R10): emb_bf [50001][128]
// (row 50000 = zeros, cols 100..127 = 0), Wc [1024][640] + cb, 4 epilogue
// weights (bf16, zero-padded), ids_pad [131080] (tail -> 50000 = zero row).
#define O1 6400128   // emb_bf
#define O2 7055488   // Wc
#define O3 8104064   // wt_sc
#define O4 10201216  // wt_fic
#define O5 12298368  // wt_fus
#define O6 13346944  // wt_out
#define OT 13478024
__global__ __launch_bounds__(256) void prep_all(
    const int* __restrict__ text_ids, const float* __restrict__ emb,
    const float* __restrict__ w2, const float* __restrict__ w3,
    const float* __restrict__ w4, const float* __restrict__ w5,
    const float* __restrict__ b2, const float* __restrict__ b3,
    const float* __restrict__ b4, const float* __restrict__ b5,
    const float* __restrict__ sc_w, const float* __restrict__ fic_w,
    const float* __restrict__ fus_w, const float* __restrict__ out_w,
    __hip_bfloat16* __restrict__ emb_bf, __hip_bfloat16* __restrict__ Wc,
    float* __restrict__ cb, __hip_bfloat16* __restrict__ wt_sc,
    __hip_bfloat16* __restrict__ wt_fic, __hip_bfloat16* __restrict__ wt_fus,
    __hip_bfloat16* __restrict__ wt_out, int* __restrict__ ids_pad) {
  for (int v = blockIdx.x * 256 + threadIdx.x; v < OT / 4;
       v += gridDim.x * 256) {
    const int idx = v * 4;
    if (idx < O1) {                       // emb_bf
      const int row = idx >> 7, e = idx & 127;
      float4 f = make_float4(0.f, 0.f, 0.f, 0.f);
      if (row < 50000 && e < 100)          // e in {0,4,..,96}: e+3<=99 valid
        f = *(const float4*)(emb + row * 100 + e);
      *(short4v*)(emb_bf + idx) =
          (short4v){bf16of(f.x), bf16of(f.y), bf16of(f.z), bf16of(f.w)};
    } else if (idx < O2) {                // Wc + cb
      const int t = idx - O1;
      const int n = t / 640, k = t % 640;  // 640%4==0 -> same n, same dh
      const int h = 2 + (n >> 8), kc = n & 255;
      const int dh = k >> 7, e = k & 127;
      const float* w = (h == 2) ? w2 : (h == 3) ? w3 : (h == 4) ? w4 : w5;
      short4v o;
#pragma unroll
      for (int i = 0; i < 4; ++i)
        o[i] = (dh < h && e + i < 100) ? bf16of(w[(kc * 100 + e + i) * h + dh])
                                       : (short)0;
      *(short4v*)(Wc + t) = o;
      if (k == 0) {
        const float* bb = (h == 2) ? b2 : (h == 3) ? b3 : (h == 4) ? b4 : b5;
        cb[n] = bb[kc];
      }
    } else if (idx < O3) {                // sc: [1000][1024] -> [1024][1024]
      const int t = idx - O2;
      const int n = t >> 10, k = t & 1023;
      float4 f = make_float4(0.f, 0.f, 0.f, 0.f);
      if (n < 1000) f = *(const float4*)(sc_w + n * 1024 + k);
      *(short4v*)(wt_sc + t) =
          (short4v){bf16of(f.x), bf16of(f.y), bf16of(f.z), bf16of(f.w)};
    } else if (idx < O4) {                // fic: [1000][2000] -> [1024][2048]
      const int t = idx - O3;
      const int n = t >> 11, k = t & 2047;
      float4 f = make_float4(0.f, 0.f, 0.f, 0.f);
      if (n < 1000 && k < 2000) f = *(const float4*)(fic_w + n * 2000 + k);
      *(short4v*)(wt_fic + t) =
          (short4v){bf16of(f.x), bf16of(f.y), bf16of(f.z), bf16of(f.w)};
    } else if (idx < O5) {                // fus: [1000][2000] -> [1024][2048]
      const int t = idx - O4;
      const int n = t >> 11, k = t & 2047;
      float4 f = make_float4(0.f, 0.f, 0.f, 0.f);
      if (n < 1000 && k < 2000) f = *(const float4*)(fus_w + n * 2000 + k);
      *(short4v*)(wt_fus + t) =
          (short4v){bf16of(f.x), bf16of(f.y), bf16of(f.z), bf16of(f.w)};
    } else if (idx < O6) {                // out: [1000][1000] -> [1024][1024]
      const int t = idx - O5;
      const int n = t >> 10, k = t & 1023;
      float4 f = make_float4(0.f, 0.f, 0.f, 0.f);
      if (n < 1000 && k < 1000) f = *(const float4*)(out_w + n * 1000 + k);
      *(short4v*)(wt_out + t) =
          (short4v){bf16of(f.x), bf16of(f.y), bf16of(f.z), bf16of(f.w)};
    } else {                              // ids_pad
      const int t = idx - O6;
      if (t + 3 < 131072) {
        *(int4*)(ids_pad + t) = *(const int4*)(text_ids + t);
      } else {
#pragma unroll
        for (int i = 0; i < 4; ++i)
          ids_pad[t + i] = (t + i < 131072) ? text_ids[t + i] : 50000;
      }
    }
  }
}

// ---------------------------------------------------------------------------
// Implicit-GEMM conv + bias + relu + maxpool; persistent per-(batch, nb) block.
// R10-VERIFIED 256x256 version (169.9-170.3 us): one block = batch b x N-tile
// nb, 8 waves (2Mx4N, wave tile 128x64 -> 0.375 LDS-reads/MFMA), BK=64, LDS
// dbuf 128 KB (1 blk/CU); 2 M-subtiles through ONE continuous counted-
// vmcnt(8) pipeline; max-fold at subtile boundary (exactly associative);
// in-block maxpool -> direct stores; emits e_bf. [R15: fp8 failed accuracy
// (0.906 > 0.8); R11/R14 128^2 variant is 4-5 us slower (worse read ratio).]
__global__ __launch_bounds__(512, 2) void conv_mfma(const __hip_bfloat16* __restrict__ Eb_,
                                                    const int* __restrict__ ids_pad,
                                                    const __hip_bfloat16* __restrict__ Wc_,
                                                    const float* __restrict__ cb,
                                                    float* __restrict__ e_out,
                                                    __hip_bfloat16* __restrict__ e_bf) {
  __shared__ __align__(16) short As[2][256 * 64];  // 64 KB
  __shared__ __align__(16) short Bs[2][256 * 64];  // 64 KB
  __shared__ int ids_s[520];                       // 516 used
  __shared__ float pm_s[8][64];
  const int g = blockIdx.x;
  const int xcd = g & 7, i = g >> 3;
  const int nb = 3 - (i & 3);            // long (nb=3) blocks dispatch first
  const int b = ((i >> 2) << 3) | xcd;   // 0..255; siblings share xcd
  const int N0 = nb << 8;
  const int nt = (2 + nb) * 2;           // K-steps of 64 per subtile: 4/6/8/10
  const int NS = nt * 2;                 // total steps (2 M-subtiles)
  const int tid = threadIdx.x;
  const int lane = tid & 63;
  const int wid = tid >> 6;
  const int wr = wid >> 2, wc = wid & 3;  // 2x4 wave grid; wave tile 128x64
  const short* Eb = (const short*)Eb_;
  const short* Wc = (const short*)Wc_;

  ids_s[tid] = ids_pad[b * 512 + tid];                           // 0..511
  if (tid < 4) ids_s[512 + tid] = ids_pad[b * 512 + 512 + tid];  // 512..515
  __syncthreads();

  f32x4 acc[8][4];
#pragma unroll
  for (int ii = 0; ii < 8; ++ii)
#pragma unroll
    for (int jj = 0; jj < 4; ++jj) acc[ii][jj] = (f32x4){0.f, 0.f, 0.f, 0.f};
  float pm[4] = {-3.0e38f, -3.0e38f, -3.0e38f, -3.0e38f};

  // Stage one BK=64 slab of A and B. LDS chunk (row,cs) holds global col
  // chunk (cs ^ (row&7)) -- involution pair with the swizzled read.
  auto STAGE = [&](int buf, int step) {
    const int sub = (step >= nt);
    const int ms = sub ? 256 : 0;
    const int k0 = (step - (sub ? nt : 0)) << 6;
    const int dh = k0 >> 7, e0 = k0 & 127;   // 64-col slab lies in one dh
#pragma unroll
    for (int ii = 0; ii < 4; ++ii) {
      const int c = tid + (ii << 9);         // 0..2047
      const int row = c >> 3, cs = c & 7;
      const int scs = cs ^ (row & 7);
      const int id = ids_s[ms + row + dh];   // lgkm read; keeps vmcnt pure
      gld_lds16(Eb + ((long)id << 7) + e0 + scs * 8, &As[buf][c * 8]);
      gld_lds16(Wc + (long)(N0 + row) * 640 + k0 + scs * 8, &Bs[buf][c * 8]);
    }
  };

  STAGE(0, 0);
  for (int t = 0; t < NS; ++t) {
    if (t + 1 < NS) {
      STAGE((t + 1) & 1, t + 1);
      asm volatile("s_waitcnt vmcnt(8)" ::: "memory");   // stage(t) done only
    } else {
      asm volatile("s_waitcnt vmcnt(0)" ::: "memory");
    }
    __builtin_amdgcn_s_barrier();          // A: stage(t) visible to all waves
    const short* Ab = As[t & 1];
    const short* Bb = Bs[t & 1];
#pragma unroll
    for (int ks = 0; ks < 2; ++ks) {
      const int csq = ks * 4 + (lane >> 4);
      short8 av[8], bv[4];
#pragma unroll
      for (int mf = 0; mf < 8; ++mf) {
        const int row = wr * 128 + mf * 16 + (lane & 15);
        av[mf] = *(const short8*)&Ab[row * 64 + (csq ^ (row & 7)) * 8];
      }
#pragma unroll
      for (int nf = 0; nf < 4; ++nf) {
        const int row = wc * 64 + nf * 16 + (lane & 15);
        bv[nf] = *(const short8*)&Bb[row * 64 + (csq ^ (row & 7)) * 8];
      }
#pragma unroll
      for (int mf = 0; mf < 8; ++mf)
#pragma unroll
        for (int nf = 0; nf < 4; ++nf)
          acc[mf][nf] = __builtin_amdgcn_mfma_f32_16x16x32_bf16(av[mf], bv[nf], acc[mf][nf], 0, 0, 0);
    }
    // Subtile-boundary fold: max is exactly associative; reset acc.
    if (t == nt - 1 || t == NS - 1) {
      const bool masked = (t == NS - 1);   // subtile 1: t_global = 256 + tloc
#pragma unroll
      for (int nf = 0; nf < 4; ++nf) {
#pragma unroll
        for (int mf = 0; mf < 8; ++mf) {
          const int tloc = wr * 128 + mf * 16 + (lane >> 4) * 4;
#pragma unroll
          for (int r = 0; r < 4; ++r) {
            if (!masked || (tloc + r <= 254 - nb))
              pm[nf] = fmaxf(pm[nf], acc[mf][nf][r]);
            acc[mf][nf][r] = 0.f;
          }
        }
      }
    }
    asm volatile("s_waitcnt lgkmcnt(0)" ::: "memory");
    __builtin_amdgcn_s_barrier();          // B: reads done before buf reuse
  }

  // Cross-wr combine in LDS, then bias+relu+store (no atomics).
#pragma unroll
  for (int nf = 0; nf < 4; ++nf) {
    float p = pm[nf];
    p = fmaxf(p, __shfl_xor(p, 16, 64));
    p = fmaxf(p, __shfl_xor(p, 32, 64));
    if ((lane >> 4) == 0) pm_s[wid][nf * 16 + (lane & 15)] = p;
  }
  __syncthreads();
  if (tid < 256) {
    const int wcx = tid >> 6, off = tid & 63;
    const int n = N0 + wcx * 64 + off;
    const float v0 = fmaxf(pm_s[wcx][off], pm_s[4 + wcx][off]);
    const float v = fmaxf(v0 + cb[n], 0.f);  // relu(max+bias) == max(relu)
    e_out[b * 1024 + n] = v;
    e_bf[b * 1024 + n] = __float2bfloat16(v);
  }
}

// ---------------------------------------------------------------------------
// 64x128-tile epilogue GEMM body (4 waves 2x2, wave tile 32x64, BK=64,
// swizzled LDS, counted vmcnt(6) depth-1 pipeline).
template<int ACT, int OUTBF>
__device__ __forceinline__ void gemm64_body(const short* __restrict__ A, int lda,
                                            const short* __restrict__ W, int ldw,
                                            const float* __restrict__ bias,
                                            void* __restrict__ Cv, int ldc,
                                            int N, int K, int cofs, int M0, int N0,
                                            short* As0, short* As1,
                                            short* Bs0, short* Bs1) {
  const int tid = threadIdx.x, lane = tid & 63;
  const int wid = tid >> 6;
  const int wr = wid >> 1, wc = wid & 1;
  short* Asb[2] = {As0, As1};
  short* Bsb[2] = {Bs0, Bs1};

  f32x4 acc[2][4];
#pragma unroll
  for (int i = 0; i < 2; ++i)
#pragma unroll
    for (int j = 0; j < 4; ++j) acc[i][j] = (f32x4){0.f, 0.f, 0.f, 0.f};

  auto STAGE = [&](int buf, int k0) {
#pragma unroll
    for (int i = 0; i < 2; ++i) {          // A: 512 chunks (64 rows)
      const int c = tid + (i << 8);
      const int row = c >> 3, cs = c & 7;
      const int scs = cs ^ (row & 7);
      gld_lds16(A + (long)(M0 + row) * lda + k0 + scs * 8, &Asb[buf][c * 8]);
    }
#pragma unroll
    for (int i = 0; i < 4; ++i) {          // B: 1024 chunks (128 rows)
      const int c = tid + (i << 8);
      const int row = c >> 3, cs = c & 7;
      const int scs = cs ^ (row & 7);
      gld_lds16(W + (long)(N0 + row) * ldw + k0 + scs * 8, &Bsb[buf][c * 8]);
    }
  };

  const int nt = K >> 6;
  STAGE(0, 0);
  for (int t = 0; t < nt; ++t) {
    if (t + 1 < nt) {
      STAGE((t + 1) & 1, (t + 1) << 6);
      asm volatile("s_waitcnt vmcnt(6)" ::: "memory");
    } else {
      asm volatile("s_waitcnt vmcnt(0)" ::: "memory");
    }
    __builtin_amdgcn_s_barrier();
    const short* Ab = Asb[t & 1];
    const short* Bb = Bsb[t & 1];
#pragma unroll
    for (int ks = 0; ks < 2; ++ks) {
      const int csq = ks * 4 + (lane >> 4);
      short8 av[2], bv[4];
#pragma unroll
      for (int mf = 0; mf < 2; ++mf) {
        const int row = wr * 32 + mf * 16 + (lane & 15);
        av[mf] = *(const short8*)&Ab[row * 64 + (csq ^ (row & 7)) * 8];
      }
#pragma unroll
      for (int nf = 0; nf < 4; ++nf) {
        const int row = wc * 64 + nf * 16 + (lane & 15);
        bv[nf] = *(const short8*)&Bb[row * 64 + (csq ^ (row & 7)) * 8];
      }
#pragma unroll
      for (int mf = 0; mf < 2; ++mf)
#pragma unroll
        for (int nf = 0; nf < 4; ++nf)
          acc[mf][nf] = __builtin_amdgcn_mfma_f32_16x16x32_bf16(av[mf], bv[nf], acc[mf][nf], 0, 0, 0);
    }
    asm volatile("s_waitcnt lgkmcnt(0)" ::: "memory");
    __builtin_amdgcn_s_barrier();
  }

#pragma unroll
  for (int nf = 0; nf < 4; ++nf) {
    const int n = N0 + wc * 64 + nf * 16 + (lane & 15);
    const float bv = (n < N) ? bias[n] : 0.f;
#pragma unroll
    for (int mf = 0; mf < 2; ++mf) {
      const int m = M0 + wr * 32 + mf * 16 + (lane >> 4) * 4;
#pragma unroll
      for (int r = 0; r < 4; ++r) {
        float v = acc[mf][nf][r] + bv;
        if (ACT) v = tanhf(v);
        if (n < N) {
          if (OUTBF)
            ((__hip_bfloat16*)Cv)[(long)(m + r) * ldc + cofs + n] = __float2bfloat16(v);
          else
            ((float*)Cv)[(long)(m + r) * ldc + cofs + n] = v;
        }
      }
    }
  }
}

template<int ACT, int OUTBF>
__global__ __launch_bounds__(256) void gemm64(const __hip_bfloat16* __restrict__ A_,
                                              int lda,
                                              const __hip_bfloat16* __restrict__ W_,
                                              int ldw,
                                              const float* __restrict__ bias,
                                              void* __restrict__ Cv, int ldc,
                                              int N, int K) {
  __shared__ __align__(16) short As[2][64 * 64];   // 16 KB
  __shared__ __align__(16) short Bs[2][128 * 64];  // 32 KB
  gemm64_body<ACT, OUTBF>((const short*)A_, lda, (const short*)W_, ldw, bias,
                          Cv, ldc, N, K, 0, blockIdx.y << 6, blockIdx.x << 7,
                          As[0], As[1], Bs[0], Bs[1]);
}

// Fused u_sc (z=0, linear) + u_fic (z=1, tanh) -> cat_sc_bf[:, z*1000 + n]
__global__ __launch_bounds__(256) void gemm64_sc_fic(
    const __hip_bfloat16* __restrict__ e_bf,
    const __hip_bfloat16* __restrict__ cat_mm_bf,
    const __hip_bfloat16* __restrict__ wt_sc,
    const __hip_bfloat16* __restrict__ wt_fic,
    const float* __restrict__ sc_b, const float* __restrict__ fic_b,
    __hip_bfloat16* __restrict__ cat_sc) {
  __shared__ __align__(16) short As[2][64 * 64];
  __shared__ __align__(16) short Bs[2][128 * 64];
  const int z = blockIdx.z;
  if (z == 0)
    gemm64_body<0, 1>((const short*)e_bf, 1024, (const short*)wt_sc, 1024, sc_b,
                      cat_sc, 2048, 1000, 1024, 0, blockIdx.y << 6,
                      blockIdx.x << 7, As[0], As[1], Bs[0], Bs[1]);
  else
    gemm64_body<1, 1>((const short*)cat_mm_bf, 2048, (const short*)wt_fic, 2048,
                      fic_b, cat_sc, 2048, 1000, 2048, 1000, blockIdx.y << 6,
                      blockIdx.x << 7, As[0], As[1], Bs[0], Bs[1]);
}

// ---------------------------------------------------------------------------
// Fused heads: per block b -- u_t (wave reduce), s1, then cat_mm_bf[b,:1000]=
// u_mm, [1000:2000]=u_mlp (s2 recomputed per api column), [2000:2048]=0.
__global__ __launch_bounds__(256) void k_heads(const float* __restrict__ e_buf,
                                               const float* __restrict__ W,
                                               const float* __restrict__ bias,
                                               const float* __restrict__ api,
                                               const float* __restrict__ mlp_w1,
                                               const float* __restrict__ mlp_b1,
                                               const float* __restrict__ mlp_w2,
                                               const float* __restrict__ mlp_b2,
                                               __hip_bfloat16* __restrict__ cat) {
  const int b = blockIdx.x, tid = threadIdx.x;
  float4 a = *(const float4*)(e_buf + b * 1024 + tid * 4);
  float acc[8];
#pragma unroll
  for (int f = 0; f < 8; ++f) {
    float4 w = *(const float4*)(W + f * 1024 + tid * 4);
    acc[f] = a.x * w.x + a.y * w.y + a.z * w.z + a.w * w.w;
  }
#pragma unroll
  for (int f = 0; f < 8; ++f)
    for (int off = 32; off; off >>= 1) acc[f] += __shfl_down(acc[f], off);
  __shared__ float red[4][8];
  __shared__ float ut_s[8];
  __shared__ float s1_s;
  if ((tid & 63) == 0) {
#pragma unroll
    for (int f = 0; f < 8; ++f) red[tid >> 6][f] = acc[f];
  }
  __syncthreads();
  if (tid == 0) {
    float s = 0.f;
#pragma unroll
    for (int f = 0; f < 8; ++f)
      ut_s[f] = red[0][f] + red[1][f] + red[2][f] + red[3][f] + bias[f];
#pragma unroll
    for (int f = 0; f < 8; ++f) {
      float t1 = 0.f;
#pragma unroll
      for (int fp = 0; fp < 8; ++fp) t1 += mlp_w1[f * 16 + fp] * ut_s[fp];
      s += t1 * mlp_w2[f];
    }
    s1_s = s;
  }
  __syncthreads();
  const float s1v = s1_s;
#pragma unroll
  for (int i = 0; i < 4; ++i) {
    const int j = tid + i * 256;           // 0..1023
    if (j < 1000) {
      float ap[8];
#pragma unroll
      for (int fp = 0; fp < 8; ++fp) ap[fp] = api[fp * 1000 + j];
      float umm = 0.f;
#pragma unroll
      for (int f = 0; f < 8; ++f) umm += ut_s[f] * ap[f];
      float s2 = mlp_b2[0];
#pragma unroll
      for (int f = 0; f < 8; ++f) {
        float t2 = mlp_b1[f];
#pragma unroll
        for (int fp = 0; fp < 8; ++fp) t2 += mlp_w1[f * 16 + 8 + fp] * ap[fp];
        s2 += t2 * mlp_w2[f];
      }
      cat[b * 2048 + j] = __float2bfloat16(umm);
      cat[b * 2048 + 1000 + j] = __float2bfloat16(tanhf(s1v + s2));
    }
  }
  if (tid < 48) cat[b * 2048 + 2000 + tid] = __float2bfloat16(0.f);
}

// ---------------------------------------------------------------------------
// FALLBACK (round-0 f32 path) — used only if ws_size is too small.
__global__ __launch_bounds__(256) void transpose_w(const float* __restrict__ w,
                                                   float* __restrict__ wt, int EH) {
  int idx = blockIdx.x * 256 + threadIdx.x;
  if (idx >= 256 * EH) return;
  int k = idx / EH, r = idx % EH;
  wt[r * 256 + k] = w[idx];
}

template<int H>
__global__ __launch_bounds__(256) void conv_pool(const int* __restrict__ ids,
                                                 const float* __restrict__ emb,
                                                 const float* __restrict__ wt,
                                                 const float* __restrict__ cbias,
                                                 float* __restrict__ e_out,
                                                 int hidx) {
  const int b = blockIdx.y;
  const int t0 = blockIdx.x * 32;
  const int L = 512 - H + 1;
  __shared__ float4 xs4[100][10];
  float* xs = (float*)xs4;
  const int tid = threadIdx.x;
  const int WIN = 32 + H - 1;
  for (int idx = tid; idx < WIN * 25; idx += 256) {
    int p = idx / 25, c = idx % 25;
    int s = t0 + p;
    float4 v = make_float4(0.f, 0.f, 0.f, 0.f);
    if (s < 512) {
      int id = ids[b * 512 + s];
      v = *(const float4*)(emb + (long)id * 100 + c * 4);
    }
    xs[(4 * c + 0) * 40 + p] = v.x;
    xs[(4 * c + 1) * 40 + p] = v.y;
    xs[(4 * c + 2) * 40 + p] = v.z;
    xs[(4 * c + 3) * 40 + p] = v.w;
  }
  __syncthreads();
  const int k = tid;
  float acc[32];
#pragma unroll
  for (int t = 0; t < 32; ++t) acc[t] = 0.f;
  const float* wk = wt + k;
  for (int e = 0; e < 100; ++e) {
    float win[36];
#pragma unroll
    for (int i = 0; i < 9; ++i)
      *(float4*)&win[i * 4] = *(const float4*)&xs[e * 40 + i * 4];
    float wr[H];
#pragma unroll
    for (int dh = 0; dh < H; ++dh) wr[dh] = wk[(e * H + dh) * 256];
#pragma unroll
    for (int t = 0; t < 32; ++t) {
      float s = acc[t];
#pragma unroll
      for (int dh = 0; dh < H; ++dh) s = fmaf(wr[dh], win[t + dh], s);
      acc[t] = s;
    }
  }
  const float bk = cbias[k];
  float m = 0.f;
#pragma unroll
  for (int t = 0; t < 32; ++t) {
    if (t0 + t < L) m = fmaxf(m, fmaxf(acc[t] + bk, 0.f));
  }
  atomicMax((int*)&e_out[b * 1024 + hidx * 256 + k], __float_as_int(m));
}

__global__ __launch_bounds__(256) void k_ut_s1(const float* __restrict__ e_buf,
                                               const float* __restrict__ W,
                                               const float* __restrict__ bias,
                                               const float* __restrict__ mlp_w1,
                                               const float* __restrict__ mlp_w2,
                                               float* __restrict__ u_t,
                                               float* __restrict__ s1) {
  const int b = blockIdx.x, tid = threadIdx.x;
  float4 a = *(const float4*)(e_buf + b * 1024 + tid * 4);
  float acc[8];
#pragma unroll
  for (int f = 0; f < 8; ++f) {
    float4 w = *(const float4*)(W + f * 1024 + tid * 4);
    acc[f] = a.x * w.x + a.y * w.y + a.z * w.z + a.w * w.w;
  }
#pragma unroll
  for (int f = 0; f < 8; ++f)
    for (int off = 32; off; off >>= 1) acc[f] += __shfl_down(acc[f], off);
  __shared__ float red[4][8];
  if ((tid & 63) == 0) {
#pragma unroll
    for (int f = 0; f < 8; ++f) red[tid >> 6][f] = acc[f];
  }
  __syncthreads();
  if (tid == 0) {
    float ut[8];
#pragma unroll
    for (int f = 0; f < 8; ++f) {
      ut[f] = red[0][f] + red[1][f] + red[2][f] + red[3][f] + bias[f];
      u_t[b * 8 + f] = ut[f];
    }
    float s = 0.f;
#pragma unroll
    for (int f = 0; f < 8; ++f) {
      float t1 = 0.f;
#pragma unroll
      for (int fp = 0; fp < 8; ++fp) t1 += mlp_w1[f * 16 + fp] * ut[fp];
      s += t1 * mlp_w2[f];
    }
    s1[b] = s;
  }
}

__global__ __launch_bounds__(256) void k_s2(const float* __restrict__ api,
                                            const float* __restrict__ mlp_w1,
                                            const float* __restrict__ mlp_b1,
                                            const float* __restrict__ mlp_w2,
                                            const float* __restrict__ mlp_b2,
                                            float* __restrict__ s2) {
  int a = blockIdx.x * 256 + threadIdx.x;
  if (a >= 1000) return;
  float ap[8];
#pragma unroll
  for (int fp = 0; fp < 8; ++fp) ap[fp] = api[fp * 1000 + a];
  float s = mlp_b2[0];
#pragma unroll
  for (int f = 0; f < 8; ++f) {
    float t2 = mlp_b1[f];
#pragma unroll
    for (int fp = 0; fp < 8; ++fp) t2 += mlp_w1[f * 16 + 8 + fp] * ap[fp];
    s += t2 * mlp_w2[f];
  }
  s2[a] = s;
}

__global__ __launch_bounds__(256) void k_cat_f32(const float* __restrict__ u_t,
                                                 const float* __restrict__ api,
                                                 const float* __restrict__ s1,
                                                 const float* __restrict__ s2,
                                                 float* __restrict__ cat_mm) {
  int j = blockIdx.x * 256 + threadIdx.x;
  int b = blockIdx.y;
  if (j >= 2000) return;
  if (j < 1000) {
    float v = 0.f;
#pragma unroll
    for (int f = 0; f < 8; ++f) v += u_t[b * 8 + f] * api[f * 1000 + j];
    cat_mm[b * 2000 + j] = v;
  } else {
    cat_mm[b * 2000 + j] = tanhf(s1[b] + s2[j - 1000]);
  }
}

template<int ACT>
__global__ __launch_bounds__(256) void gemm_tn(const float* __restrict__ A, int lda,
                                               const float* __restrict__ W, int ldw,
                                               const float* __restrict__ bias,
                                               float* __restrict__ C, int ldc,
                                               int M, int N, int K) {
  __shared__ float As[8][33];
  __shared__ float Ws[8][33];
  const int n0 = blockIdx.x * 32, m0 = blockIdx.y * 32;
  const int tid = threadIdx.x;
  const int tx = tid % 16, ty = tid / 16;
  const int ms = tid / 8, ks = tid % 8;
  float acc[2][2] = {{0.f, 0.f}, {0.f, 0.f}};
  for (int k0 = 0; k0 < K; k0 += 8) {
    As[ks][ms] = A[(m0 + ms) * lda + k0 + ks];
    int n = n0 + ms;
    Ws[ks][ms] = (n < N) ? W[n * ldw + k0 + ks] : 0.f;
    __syncthreads();
#pragma unroll
    for (int kk = 0; kk < 8; ++kk) {
      float a0 = As[kk][ty], a1 = As[kk][ty + 16];
      float w0 = Ws[kk][tx], w1 = Ws[kk][tx + 16];
      acc[0][0] = fmaf(a0, w0, acc[0][0]);
      acc[0][1] = fmaf(a0, w1, acc[0][1]);
      acc[1][0] = fmaf(a1, w0, acc[1][0]);
      acc[1][1] = fmaf(a1, w1, acc[1][1]);
    }
    __syncthreads();
  }
#pragma unroll
  for (int i = 0; i < 2; ++i)
#pragma unroll
    for (int j = 0; j < 2; ++j) {
      int m = m0 + ty + 16 * i, n = n0 + tx + 16 * j;
      if (n < N) {
        float v = acc[i][j] + bias[n];
        if (ACT) v = tanhf(v);
        C[m * ldc + n] = v;
      }
    }
}

// ---------------------------------------------------------------------------
extern "C" void kernel_launch(void* const* d_in, const int* in_sizes, int n_in,
                              void* d_out, int out_size, void* d_ws, size_t ws_size,
                              hipStream_t stream) {
  const int*   text_ids  = (const int*)d_in[0];
  const float* emb       = (const float*)d_in[1];
  const float* cw2       = (const float*)d_in[2];
  const float* cb2       = (const float*)d_in[3];
  const float* cw3       = (const float*)d_in[4];
  const float* cb3       = (const float*)d_in[5];
  const float* cw4       = (const float*)d_in[6];
  const float* cb4       = (const float*)d_in[7];
  const float* cw5       = (const float*)d_in[8];
  const float* cb5       = (const float*)d_in[9];
  const float* sc_w      = (const float*)d_in[10];
  const float* sc_b      = (const float*)d_in[11];
  const float* fic_fc_w  = (const float*)d_in[12];
  const float* fic_fc_b  = (const float*)d_in[13];
  const float* api       = (const float*)d_in[14];
  const float* mlp_w1    = (const float*)d_in[15];
  const float* mlp_b1    = (const float*)d_in[16];
  const float* mlp_w2    = (const float*)d_in[17];
  const float* mlp_b2    = (const float*)d_in[18];
  const float* fic_fcl_w = (const float*)d_in[19];
  const float* fic_fcl_b = (const float*)d_in[20];
  const float* fusion_w  = (const float*)d_in[21];
  const float* fusion_b  = (const float*)d_in[22];
  const float* out_w     = (const float*)d_in[23];
  const float* out_b     = (const float*)d_in[24];

  float* ws = (float*)d_ws;
  float* e_buf = ws;                       // 262144 f32
  float* cbias = e_buf + 262144;           // 1024
  // bf16 region (offset 263168*4 B, 16-aligned)
  __hip_bfloat16* bfb       = (__hip_bfloat16*)(cbias + 1024);
  __hip_bfloat16* e_bf      = bfb;                  // 262144 (256x1024)
  __hip_bfloat16* cat_mm_bf = e_bf + 262144;        // 524288 (256x2048)
  __hip_bfloat16* cat_sc_bf = cat_mm_bf + 524288;   // 524288 (256x2048)
  __hip_bfloat16* u_mmf_bf  = cat_sc_bf + 524288;   // 262144 (256x1024)
  __hip_bfloat16* emb_bf    = u_mmf_bf + 262144;    // 6400128 (50001x128)
  __hip_bfloat16* Wc        = emb_bf + 6400128;     // 655360
  __hip_bfloat16* wt_sc     = Wc + 655360;          // 1048576
  __hip_bfloat16* wt_fic    = wt_sc + 1048576;      // 2097152
  __hip_bfloat16* wt_fus    = wt_fic + 2097152;     // 2097152
  __hip_bfloat16* wt_out    = wt_fus + 2097152;     // 1048576
  int* ids_pad = (int*)(wt_out + 1048576);          // 131080 ints
  const size_t need_fast =
      263168UL * 4 + 14919808UL * 2 + 131080UL * 4;  // ~31.4 MB

  if (ws_size >= need_fast) {
    prep_all<<<4096, 256, 0, stream>>>(text_ids, emb, cw2, cw3, cw4, cw5,
                                       cb2, cb3, cb4, cb5, sc_w, fic_fcl_w,
                                       fusion_w, out_w, emb_bf, Wc, cbias,
                                       wt_sc, wt_fic, wt_fus, wt_out, ids_pad);
    conv_mfma<<<1024, 512, 0, stream>>>(emb_bf, ids_pad, Wc, cbias, e_buf, e_bf);
    k_heads<<<256, 256, 0, stream>>>(e_buf, fic_fc_w, fic_fc_b, api, mlp_w1,
                                     mlp_b1, mlp_w2, mlp_b2, cat_mm_bf);
    gemm64_sc_fic<<<dim3(8, 4, 2), 256, 0, stream>>>(e_bf, cat_mm_bf, wt_sc,
                                                     wt_fic, sc_b, fic_fcl_b,
                                                     cat_sc_bf);
    gemm64<0, 1><<<dim3(8, 4), 256, 0, stream>>>(cat_sc_bf, 2048, wt_fus, 2048,
                                                 fusion_b, u_mmf_bf, 1024,
                                                 1000, 2048);
    gemm64<0, 0><<<dim3(8, 4), 256, 0, stream>>>(u_mmf_bf, 1024, wt_out, 1024,
                                                 out_b, d_out, 1000, 1000, 1024);
  } else {
    // f32 fallback (round-0 verified path) — needs zeroed e_buf for atomicMax
    hipMemsetAsync(e_buf, 0, 262144 * sizeof(float), stream);
    float* u_t    = (float*)bfb;            // 2048
    float* s1     = u_t + 2048;             // 256
    float* s2     = s1 + 256;               // 1024
    float* cat_mm = s2 + 1024;              // 512000
    float* cat_sc = cat_mm + 512000;        // 512000
    float* u_mmf  = cat_sc + 512000;        // 256000
    float* wt     = u_mmf + 256000;         // 358400
    transpose_w<<<200, 256, 0, stream>>>(cw2, wt + 0,      200);
    transpose_w<<<300, 256, 0, stream>>>(cw3, wt + 51200,  300);
    transpose_w<<<400, 256, 0, stream>>>(cw4, wt + 128000, 400);
    transpose_w<<<500, 256, 0, stream>>>(cw5, wt + 230400, 500);
    conv_pool<2><<<dim3(16, 256), 256, 0, stream>>>(text_ids, emb, wt + 0,      cb2, e_buf, 0);
    conv_pool<3><<<dim3(16, 256), 256, 0, stream>>>(text_ids, emb, wt + 51200,  cb3, e_buf, 1);
    conv_pool<4><<<dim3(16, 256), 256, 0, stream>>>(text_ids, emb, wt + 128000, cb4, e_buf, 2);
    conv_pool<5><<<dim3(16, 256), 256, 0, stream>>>(text_ids, emb, wt + 230400, cb5, e_buf, 3);
    k_ut_s1<<<256, 256, 0, stream>>>(e_buf, fic_fc_w, fic_fc_b, mlp_w1, mlp_w2, u_t, s1);
    k_s2<<<4, 256, 0, stream>>>(api, mlp_w1, mlp_b1, mlp_w2, mlp_b2, s2);
    k_cat_f32<<<dim3(8, 256), 256, 0, stream>>>(u_t, api, s1, s2, cat_mm);
    gemm_tn<0><<<dim3(32, 8), 256, 0, stream>>>(e_buf, 1024, sc_w, 1024, sc_b,
                                                cat_sc, 2000, 256, 1000, 1024);
    gemm_tn<1><<<dim3(32, 8), 256, 0, stream>>>(cat_mm, 2000, fic_fcl_w, 2000, fic_fcl_b,
                                                cat_sc + 1000, 2000, 256, 1000, 2000);
    gemm_tn<0><<<dim3(32, 8), 256, 0, stream>>>(cat_sc, 2000, fusion_w, 2000, fusion_b,
                                                u_mmf, 1000, 256, 1000, 2000);
    gemm_tn<0><<<dim3(32, 8), 256, 0, stream>>>(u_mmf, 1000, out_w, 1000, out_b,
                                                (float*)d_out, 1000, 256, 1000, 1000);
  }
}

// Round 18
// 243.942 us; speedup vs baseline: 1.0526x; 1.0523x over previous
//
#include <hip/hip_runtime.h>
#include <hip/hip_bf16.h>
#include <math.h>

// Model dims: V=50000, A=1000, E=100, K=256, F=8, B=256, S=512, KS=(2,3,4,5)

typedef __attribute__((ext_vector_type(8))) short short8;
typedef __attribute__((ext_vector_type(4))) short short4v;
typedef __attribute__((ext_vector_type(4))) float f32x4;

__device__ __forceinline__ void gld_lds16(const void* g, void* l) {
  __builtin_amdgcn_global_load_lds(
      (const __attribute__((address_space(1))) unsigned int*)g,
      (__attribute__((address_space(3))) unsigned int*)l, 16, 0, 0);
}

__device__ __forceinline__ short bf16of(float f) {
  union { float f; unsigned u; } x; x.f = f;
  unsigned r = (x.u + 0x7fff + ((x.u >> 16) & 1)) >> 16;   // RNE, matches __float2bfloat16
  return (short)r;
}

// ---------------------------------------------------------------------------
// One grid-stride prep kernel, vec4 (verified R10): emb_bf [50001][128]
// (row 50000 = zeros, cols 100..127 = 0), Wc [1024][640] + cb, 4 epilogue
// weights (bf16, zero-padded), ids_pad [131080] (tail -> 50000 = zero row).
#define O1 6400128   // emb_bf
#define O2 7055488   // Wc
#define O3 8104064   // wt_sc
#define O4 10201216  // wt_fic
#define O5 12298368  // wt_fus
#define O6 13346944  // wt_out
#define OT 13478024
__global__ __launch_bounds__(256) void prep_all(
    const int* __restrict__ text_ids, const float* __restrict__ emb,
    const float* __restrict__ w2, const float* __restrict__ w3,
    const float* __restrict__ w4, const float* __restrict__ w5,
    const float* __restrict__ b2, const float* __restrict__ b3,
    const float* __restrict__ b4, const float* __restrict__ b5,
    const float* __restrict__ sc_w, const float* __restrict__ fic_w,
    const float* __restrict__ fus_w, const float* __restrict__ out_w,
    __hip_bfloat16* __restrict__ emb_bf, __hip_bfloat16* __restrict__ Wc,
    float* __restrict__ cb, __hip_bfloat16* __restrict__ wt_sc,
    __hip_bfloat16* __restrict__ wt_fic, __hip_bfloat16* __restrict__ wt_fus,
    __hip_bfloat16* __restrict__ wt_out, int* __restrict__ ids_pad) {
  for (int v = blockIdx.x * 256 + threadIdx.x; v < OT / 4;
       v += gridDim.x * 256) {
    const int idx = v * 4;
    if (idx < O1) {                       // emb_bf
      const int row = idx >> 7, e = idx & 127;
      float4 f = make_float4(0.f, 0.f, 0.f, 0.f);
      if (row < 50000 && e < 100)          // e in {0,4,..,96}: e+3<=99 valid
        f = *(const float4*)(emb + row * 100 + e);
      *(short4v*)(emb_bf + idx) =
          (short4v){bf16of(f.x), bf16of(f.y), bf16of(f.z), bf16of(f.w)};
    } else if (idx < O2) {                // Wc + cb
      const int t = idx - O1;
      const int n = t / 640, k = t % 640;  // 640%4==0 -> same n, same dh
      const int h = 2 + (n >> 8), kc = n & 255;
      const int dh = k >> 7, e = k & 127;
      const float* w = (h == 2) ? w2 : (h == 3) ? w3 : (h == 4) ? w4 : w5;
      short4v o;
#pragma unroll
      for (int i = 0; i < 4; ++i)
        o[i] = (dh < h && e + i < 100) ? bf16of(w[(kc * 100 + e + i) * h + dh])
                                       : (short)0;
      *(short4v*)(Wc + t) = o;
      if (k == 0) {
        const float* bb = (h == 2) ? b2 : (h == 3) ? b3 : (h == 4) ? b4 : b5;
        cb[n] = bb[kc];
      }
    } else if (idx < O3) {                // sc: [1000][1024] -> [1024][1024]
      const int t = idx - O2;
      const int n = t >> 10, k = t & 1023;
      float4 f = make_float4(0.f, 0.f, 0.f, 0.f);
      if (n < 1000) f = *(const float4*)(sc_w + n * 1024 + k);
      *(short4v*)(wt_sc + t) =
          (short4v){bf16of(f.x), bf16of(f.y), bf16of(f.z), bf16of(f.w)};
    } else if (idx < O4) {                // fic: [1000][2000] -> [1024][2048]
      const int t = idx - O3;
      const int n = t >> 11, k = t & 2047;
      float4 f = make_float4(0.f, 0.f, 0.f, 0.f);
      if (n < 1000 && k < 2000) f = *(const float4*)(fic_w + n * 2000 + k);
      *(short4v*)(wt_fic + t) =
          (short4v){bf16of(f.x), bf16of(f.y), bf16of(f.z), bf16of(f.w)};
    } else if (idx < O5) {                // fus: [1000][2000] -> [1024][2048]
      const int t = idx - O4;
      const int n = t >> 11, k = t & 2047;
      float4 f = make_float4(0.f, 0.f, 0.f, 0.f);
      if (n < 1000 && k < 2000) f = *(const float4*)(fus_w + n * 2000 + k);
      *(short4v*)(wt_fus + t) =
          (short4v){bf16of(f.x), bf16of(f.y), bf16of(f.z), bf16of(f.w)};
    } else if (idx < O6) {                // out: [1000][1000] -> [1024][1024]
      const int t = idx - O5;
      const int n = t >> 10, k = t & 1023;
      float4 f = make_float4(0.f, 0.f, 0.f, 0.f);
      if (n < 1000 && k < 1000) f = *(const float4*)(out_w + n * 1000 + k);
      *(short4v*)(wt_out + t) =
          (short4v){bf16of(f.x), bf16of(f.y), bf16of(f.z), bf16of(f.w)};
    } else {                              // ids_pad
      const int t = idx - O6;
      if (t + 3 < 131072) {
        *(int4*)(ids_pad + t) = *(const int4*)(text_ids + t);
      } else {
#pragma unroll
        for (int i = 0; i < 4; ++i)
          ids_pad[t + i] = (t + i < 131072) ? text_ids[t + i] : 50000;
      }
    }
  }
}

// ---------------------------------------------------------------------------
// Implicit-GEMM conv + bias + relu + maxpool; persistent per-(batch, nb) block.
// R10/R17-VERIFIED 256x256 version (169.9-170.3 us): one block = batch b x
// N-tile nb, 8 waves (2Mx4N, wave tile 128x64), BK=64, LDS dbuf 128 KB;
// 2 M-subtiles through ONE continuous counted-vmcnt(8) pipeline; max-fold at
// subtile boundary (exactly associative); in-block maxpool -> direct stores;
// emits e_bf. This is the measured structure-family plateau (~30% MfmaUtil).
__global__ __launch_bounds__(512, 2) void conv_mfma(const __hip_bfloat16* __restrict__ Eb_,
                                                    const int* __restrict__ ids_pad,
                                                    const __hip_bfloat16* __restrict__ Wc_,
                                                    const float* __restrict__ cb,
                                                    float* __restrict__ e_out,
                                                    __hip_bfloat16* __restrict__ e_bf) {
  __shared__ __align__(16) short As[2][256 * 64];  // 64 KB
  __shared__ __align__(16) short Bs[2][256 * 64];  // 64 KB
  __shared__ int ids_s[520];                       // 516 used
  __shared__ float pm_s[8][64];
  const int g = blockIdx.x;
  const int xcd = g & 7, i = g >> 3;
  const int nb = 3 - (i & 3);            // long (nb=3) blocks dispatch first
  const int b = ((i >> 2) << 3) | xcd;   // 0..255; siblings share xcd
  const int N0 = nb << 8;
  const int nt = (2 + nb) * 2;           // K-steps of 64 per subtile: 4/6/8/10
  const int NS = nt * 2;                 // total steps (2 M-subtiles)
  const int tid = threadIdx.x;
  const int lane = tid & 63;
  const int wid = tid >> 6;
  const int wr = wid >> 2, wc = wid & 3;  // 2x4 wave grid; wave tile 128x64
  const short* Eb = (const short*)Eb_;
  const short* Wc = (const short*)Wc_;

  ids_s[tid] = ids_pad[b * 512 + tid];                           // 0..511
  if (tid < 4) ids_s[512 + tid] = ids_pad[b * 512 + 512 + tid];  // 512..515
  __syncthreads();

  f32x4 acc[8][4];
#pragma unroll
  for (int ii = 0; ii < 8; ++ii)
#pragma unroll
    for (int jj = 0; jj < 4; ++jj) acc[ii][jj] = (f32x4){0.f, 0.f, 0.f, 0.f};
  float pm[4] = {-3.0e38f, -3.0e38f, -3.0e38f, -3.0e38f};

  // Stage one BK=64 slab of A and B. LDS chunk (row,cs) holds global col
  // chunk (cs ^ (row&7)) -- involution pair with the swizzled read.
  auto STAGE = [&](int buf, int step) {
    const int sub = (step >= nt);
    const int ms = sub ? 256 : 0;
    const int k0 = (step - (sub ? nt : 0)) << 6;
    const int dh = k0 >> 7, e0 = k0 & 127;   // 64-col slab lies in one dh
#pragma unroll
    for (int ii = 0; ii < 4; ++ii) {
      const int c = tid + (ii << 9);         // 0..2047
      const int row = c >> 3, cs = c & 7;
      const int scs = cs ^ (row & 7);
      const int id = ids_s[ms + row + dh];   // lgkm read; keeps vmcnt pure
      gld_lds16(Eb + ((long)id << 7) + e0 + scs * 8, &As[buf][c * 8]);
      gld_lds16(Wc + (long)(N0 + row) * 640 + k0 + scs * 8, &Bs[buf][c * 8]);
    }
  };

  STAGE(0, 0);
  for (int t = 0; t < NS; ++t) {
    if (t + 1 < NS) {
      STAGE((t + 1) & 1, t + 1);
      asm volatile("s_waitcnt vmcnt(8)" ::: "memory");   // stage(t) done only
    } else {
      asm volatile("s_waitcnt vmcnt(0)" ::: "memory");
    }
    __builtin_amdgcn_s_barrier();          // A: stage(t) visible to all waves
    const short* Ab = As[t & 1];
    const short* Bb = Bs[t & 1];
#pragma unroll
    for (int ks = 0; ks < 2; ++ks) {
      const int csq = ks * 4 + (lane >> 4);
      short8 av[8], bv[4];
#pragma unroll
      for (int mf = 0; mf < 8; ++mf) {
        const int row = wr * 128 + mf * 16 + (lane & 15);
        av[mf] = *(const short8*)&Ab[row * 64 + (csq ^ (row & 7)) * 8];
      }
#pragma unroll
      for (int nf = 0; nf < 4; ++nf) {
        const int row = wc * 64 + nf * 16 + (lane & 15);
        bv[nf] = *(const short8*)&Bb[row * 64 + (csq ^ (row & 7)) * 8];
      }
#pragma unroll
      for (int mf = 0; mf < 8; ++mf)
#pragma unroll
        for (int nf = 0; nf < 4; ++nf)
          acc[mf][nf] = __builtin_amdgcn_mfma_f32_16x16x32_bf16(av[mf], bv[nf], acc[mf][nf], 0, 0, 0);
    }
    // Subtile-boundary fold: max is exactly associative; reset acc.
    if (t == nt - 1 || t == NS - 1) {
      const bool masked = (t == NS - 1);   // subtile 1: t_global = 256 + tloc
#pragma unroll
      for (int nf = 0; nf < 4; ++nf) {
#pragma unroll
        for (int mf = 0; mf < 8; ++mf) {
          const int tloc = wr * 128 + mf * 16 + (lane >> 4) * 4;
#pragma unroll
          for (int r = 0; r < 4; ++r) {
            if (!masked || (tloc + r <= 254 - nb))
              pm[nf] = fmaxf(pm[nf], acc[mf][nf][r]);
            acc[mf][nf][r] = 0.f;
          }
        }
      }
    }
    asm volatile("s_waitcnt lgkmcnt(0)" ::: "memory");
    __builtin_amdgcn_s_barrier();          // B: reads done before buf reuse
  }

  // Cross-wr combine in LDS, then bias+relu+store (no atomics).
#pragma unroll
  for (int nf = 0; nf < 4; ++nf) {
    float p = pm[nf];
    p = fmaxf(p, __shfl_xor(p, 16, 64));
    p = fmaxf(p, __shfl_xor(p, 32, 64));
    if ((lane >> 4) == 0) pm_s[wid][nf * 16 + (lane & 15)] = p;
  }
  __syncthreads();
  if (tid < 256) {
    const int wcx = tid >> 6, off = tid & 63;
    const int n = N0 + wcx * 64 + off;
    const float v0 = fmaxf(pm_s[wcx][off], pm_s[4 + wcx][off]);
    const float v = fmaxf(v0 + cb[n], 0.f);  // relu(max+bias) == max(relu)
    e_out[b * 1024 + n] = v;
    e_bf[b * 1024 + n] = __float2bfloat16(v);
  }
}

// ---------------------------------------------------------------------------
// 64x128-tile epilogue GEMM body, BK=128 (R18): halves the serial K-step
// count of the latency-bound tail GEMMs (32->16 / 16->8 steps). 4 waves 2x2,
// wave tile 32x64, LDS 96 KB dbuf, 16-chunk involution swizzle (cs^(row&15);
// residual 2-way bank aliasing is free per m136), counted vmcnt(12) depth-1
// pipeline. K accumulation order = ascending 32-chunks (same as BK=64) ->
// bit-identical results.
template<int ACT, int OUTBF>
__device__ __forceinline__ void gemm128_body(const short* __restrict__ A, int lda,
                                             const short* __restrict__ W, int ldw,
                                             const float* __restrict__ bias,
                                             void* __restrict__ Cv, int ldc,
                                             int N, int K, int cofs, int M0, int N0,
                                             short* As0, short* As1,
                                             short* Bs0, short* Bs1) {
  const int tid = threadIdx.x, lane = tid & 63;
  const int wid = tid >> 6;
  const int wr = wid >> 1, wc = wid & 1;
  short* Asb[2] = {As0, As1};
  short* Bsb[2] = {Bs0, Bs1};

  f32x4 acc[2][4];
#pragma unroll
  for (int i = 0; i < 2; ++i)
#pragma unroll
    for (int j = 0; j < 4; ++j) acc[i][j] = (f32x4){0.f, 0.f, 0.f, 0.f};

  auto STAGE = [&](int buf, int k0) {
#pragma unroll
    for (int i = 0; i < 4; ++i) {          // A: 64 rows x 16 chunks = 1024
      const int c = tid + (i << 8);
      const int row = c >> 4, cs = c & 15;
      const int scs = cs ^ (row & 15);
      gld_lds16(A + (long)(M0 + row) * lda + k0 + scs * 8,
                &Asb[buf][row * 128 + cs * 8]);
    }
#pragma unroll
    for (int i = 0; i < 8; ++i) {          // B: 128 rows x 16 chunks = 2048
      const int c = tid + (i << 8);
      const int row = c >> 4, cs = c & 15;
      const int scs = cs ^ (row & 15);
      gld_lds16(W + (long)(N0 + row) * ldw + k0 + scs * 8,
                &Bsb[buf][row * 128 + cs * 8]);
    }
  };

  const int nt = K >> 7;                   // BK=128 steps
  STAGE(0, 0);
  for (int t = 0; t < nt; ++t) {
    if (t + 1 < nt) {
      STAGE((t + 1) & 1, (t + 1) << 7);
      asm volatile("s_waitcnt vmcnt(12)" ::: "memory");  // stage(t) done only
    } else {
      asm volatile("s_waitcnt vmcnt(0)" ::: "memory");
    }
    __builtin_amdgcn_s_barrier();
    const short* Ab = Asb[t & 1];
    const short* Bb = Bsb[t & 1];
#pragma unroll
    for (int ks = 0; ks < 4; ++ks) {       // 4 K-slices of 32
      const int csq = ks * 4 + (lane >> 4);
      short8 av[2], bv[4];
#pragma unroll
      for (int mf = 0; mf < 2; ++mf) {
        const int row = wr * 32 + mf * 16 + (lane & 15);
        av[mf] = *(const short8*)&Ab[row * 128 + (csq ^ (row & 15)) * 8];
      }
#pragma unroll
      for (int nf = 0; nf < 4; ++nf) {
        const int row = wc * 64 + nf * 16 + (lane & 15);
        bv[nf] = *(const short8*)&Bb[row * 128 + (csq ^ (row & 15)) * 8];
      }
#pragma unroll
      for (int mf = 0; mf < 2; ++mf)
#pragma unroll
        for (int nf = 0; nf < 4; ++nf)
          acc[mf][nf] = __builtin_amdgcn_mfma_f32_16x16x32_bf16(av[mf], bv[nf], acc[mf][nf], 0, 0, 0);
    }
    asm volatile("s_waitcnt lgkmcnt(0)" ::: "memory");
    __builtin_amdgcn_s_barrier();
  }

#pragma unroll
  for (int nf = 0; nf < 4; ++nf) {
    const int n = N0 + wc * 64 + nf * 16 + (lane & 15);
    const float bv = (n < N) ? bias[n] : 0.f;
#pragma unroll
    for (int mf = 0; mf < 2; ++mf) {
      const int m = M0 + wr * 32 + mf * 16 + (lane >> 4) * 4;
#pragma unroll
      for (int r = 0; r < 4; ++r) {
        float v = acc[mf][nf][r] + bv;
        if (ACT) v = tanhf(v);
        if (n < N) {
          if (OUTBF)
            ((__hip_bfloat16*)Cv)[(long)(m + r) * ldc + cofs + n] = __float2bfloat16(v);
          else
            ((float*)Cv)[(long)(m + r) * ldc + cofs + n] = v;
        }
      }
    }
  }
}

template<int ACT, int OUTBF>
__global__ __launch_bounds__(256) void gemm128(const __hip_bfloat16* __restrict__ A_,
                                               int lda,
                                               const __hip_bfloat16* __restrict__ W_,
                                               int ldw,
                                               const float* __restrict__ bias,
                                               void* __restrict__ Cv, int ldc,
                                               int N, int K) {
  __shared__ __align__(16) short As[2][64 * 128];   // 32 KB
  __shared__ __align__(16) short Bs[2][128 * 128];  // 64 KB
  gemm128_body<ACT, OUTBF>((const short*)A_, lda, (const short*)W_, ldw, bias,
                           Cv, ldc, N, K, 0, blockIdx.y << 6, blockIdx.x << 7,
                           As[0], As[1], Bs[0], Bs[1]);
}

// Fused u_sc (z=0, linear) + u_fic (z=1, tanh) -> cat_sc_bf[:, z*1000 + n]
__global__ __launch_bounds__(256) void gemm128_sc_fic(
    const __hip_bfloat16* __restrict__ e_bf,
    const __hip_bfloat16* __restrict__ cat_mm_bf,
    const __hip_bfloat16* __restrict__ wt_sc,
    const __hip_bfloat16* __restrict__ wt_fic,
    const float* __restrict__ sc_b, const float* __restrict__ fic_b,
    __hip_bfloat16* __restrict__ cat_sc) {
  __shared__ __align__(16) short As[2][64 * 128];
  __shared__ __align__(16) short Bs[2][128 * 128];
  const int z = blockIdx.z;
  if (z == 0)
    gemm128_body<0, 1>((const short*)e_bf, 1024, (const short*)wt_sc, 1024, sc_b,
                       cat_sc, 2048, 1000, 1024, 0, blockIdx.y << 6,
                       blockIdx.x << 7, As[0], As[1], Bs[0], Bs[1]);
  else
    gemm128_body<1, 1>((const short*)cat_mm_bf, 2048, (const short*)wt_fic, 2048,
                       fic_b, cat_sc, 2048, 1000, 2048, 1000, blockIdx.y << 6,
                       blockIdx.x << 7, As[0], As[1], Bs[0], Bs[1]);
}

// ---------------------------------------------------------------------------
// Fused heads: per block b -- u_t (wave reduce), s1, then cat_mm_bf[b,:1000]=
// u_mm, [1000:2000]=u_mlp (s2 recomputed per api column), [2000:2048]=0.
__global__ __launch_bounds__(256) void k_heads(const float* __restrict__ e_buf,
                                               const float* __restrict__ W,
                                               const float* __restrict__ bias,
                                               const float* __restrict__ api,
                                               const float* __restrict__ mlp_w1,
                                               const float* __restrict__ mlp_b1,
                                               const float* __restrict__ mlp_w2,
                                               const float* __restrict__ mlp_b2,
                                               __hip_bfloat16* __restrict__ cat) {
  const int b = blockIdx.x, tid = threadIdx.x;
  float4 a = *(const float4*)(e_buf + b * 1024 + tid * 4);
  float acc[8];
#pragma unroll
  for (int f = 0; f < 8; ++f) {
    float4 w = *(const float4*)(W + f * 1024 + tid * 4);
    acc[f] = a.x * w.x + a.y * w.y + a.z * w.z + a.w * w.w;
  }
#pragma unroll
  for (int f = 0; f < 8; ++f)
    for (int off = 32; off; off >>= 1) acc[f] += __shfl_down(acc[f], off);
  __shared__ float red[4][8];
  __shared__ float ut_s[8];
  __shared__ float s1_s;
  if ((tid & 63) == 0) {
#pragma unroll
    for (int f = 0; f < 8; ++f) red[tid >> 6][f] = acc[f];
  }
  __syncthreads();
  if (tid == 0) {
    float s = 0.f;
#pragma unroll
    for (int f = 0; f < 8; ++f)
      ut_s[f] = red[0][f] + red[1][f] + red[2][f] + red[3][f] + bias[f];
#pragma unroll
    for (int f = 0; f < 8; ++f) {
      float t1 = 0.f;
#pragma unroll
      for (int fp = 0; fp < 8; ++fp) t1 += mlp_w1[f * 16 + fp] * ut_s[fp];
      s += t1 * mlp_w2[f];
    }
    s1_s = s;
  }
  __syncthreads();
  const float s1v = s1_s;
#pragma unroll
  for (int i = 0; i < 4; ++i) {
    const int j = tid + i * 256;           // 0..1023
    if (j < 1000) {
      float ap[8];
#pragma unroll
      for (int fp = 0; fp < 8; ++fp) ap[fp] = api[fp * 1000 + j];
      float umm = 0.f;
#pragma unroll
      for (int f = 0; f < 8; ++f) umm += ut_s[f] * ap[f];
      float s2 = mlp_b2[0];
#pragma unroll
      for (int f = 0; f < 8; ++f) {
        float t2 = mlp_b1[f];
#pragma unroll
        for (int fp = 0; fp < 8; ++fp) t2 += mlp_w1[f * 16 + 8 + fp] * ap[fp];
        s2 += t2 * mlp_w2[f];
      }
      cat[b * 2048 + j] = __float2bfloat16(umm);
      cat[b * 2048 + 1000 + j] = __float2bfloat16(tanhf(s1v + s2));
    }
  }
  if (tid < 48) cat[b * 2048 + 2000 + tid] = __float2bfloat16(0.f);
}

// ---------------------------------------------------------------------------
// FALLBACK (round-0 f32 path) — used only if ws_size is too small.
__global__ __launch_bounds__(256) void transpose_w(const float* __restrict__ w,
                                                   float* __restrict__ wt, int EH) {
  int idx = blockIdx.x * 256 + threadIdx.x;
  if (idx >= 256 * EH) return;
  int k = idx / EH, r = idx % EH;
  wt[r * 256 + k] = w[idx];
}

template<int H>
__global__ __launch_bounds__(256) void conv_pool(const int* __restrict__ ids,
                                                 const float* __restrict__ emb,
                                                 const float* __restrict__ wt,
                                                 const float* __restrict__ cbias,
                                                 float* __restrict__ e_out,
                                                 int hidx) {
  const int b = blockIdx.y;
  const int t0 = blockIdx.x * 32;
  const int L = 512 - H + 1;
  __shared__ float4 xs4[100][10];
  float* xs = (float*)xs4;
  const int tid = threadIdx.x;
  const int WIN = 32 + H - 1;
  for (int idx = tid; idx < WIN * 25; idx += 256) {
    int p = idx / 25, c = idx % 25;
    int s = t0 + p;
    float4 v = make_float4(0.f, 0.f, 0.f, 0.f);
    if (s < 512) {
      int id = ids[b * 512 + s];
      v = *(const float4*)(emb + (long)id * 100 + c * 4);
    }
    xs[(4 * c + 0) * 40 + p] = v.x;
    xs[(4 * c + 1) * 40 + p] = v.y;
    xs[(4 * c + 2) * 40 + p] = v.z;
    xs[(4 * c + 3) * 40 + p] = v.w;
  }
  __syncthreads();
  const int k = tid;
  float acc[32];
#pragma unroll
  for (int t = 0; t < 32; ++t) acc[t] = 0.f;
  const float* wk = wt + k;
  for (int e = 0; e < 100; ++e) {
    float win[36];
#pragma unroll
    for (int i = 0; i < 9; ++i)
      *(float4*)&win[i * 4] = *(const float4*)&xs[e * 40 + i * 4];
    float wr[H];
#pragma unroll
    for (int dh = 0; dh < H; ++dh) wr[dh] = wk[(e * H + dh) * 256];
#pragma unroll
    for (int t = 0; t < 32; ++t) {
      float s = acc[t];
#pragma unroll
      for (int dh = 0; dh < H; ++dh) s = fmaf(wr[dh], win[t + dh], s);
      acc[t] = s;
    }
  }
  const float bk = cbias[k];
  float m = 0.f;
#pragma unroll
  for (int t = 0; t < 32; ++t) {
    if (t0 + t < L) m = fmaxf(m, fmaxf(acc[t] + bk, 0.f));
  }
  atomicMax((int*)&e_out[b * 1024 + hidx * 256 + k], __float_as_int(m));
}

__global__ __launch_bounds__(256) void k_ut_s1(const float* __restrict__ e_buf,
                                               const float* __restrict__ W,
                                               const float* __restrict__ bias,
                                               const float* __restrict__ mlp_w1,
                                               const float* __restrict__ mlp_w2,
                                               float* __restrict__ u_t,
                                               float* __restrict__ s1) {
  const int b = blockIdx.x, tid = threadIdx.x;
  float4 a = *(const float4*)(e_buf + b * 1024 + tid * 4);
  float acc[8];
#pragma unroll
  for (int f = 0; f < 8; ++f) {
    float4 w = *(const float4*)(W + f * 1024 + tid * 4);
    acc[f] = a.x * w.x + a.y * w.y + a.z * w.z + a.w * w.w;
  }
#pragma unroll
  for (int f = 0; f < 8; ++f)
    for (int off = 32; off; off >>= 1) acc[f] += __shfl_down(acc[f], off);
  __shared__ float red[4][8];
  if ((tid & 63) == 0) {
#pragma unroll
    for (int f = 0; f < 8; ++f) red[tid >> 6][f] = acc[f];
  }
  __syncthreads();
  if (tid == 0) {
    float ut[8];
#pragma unroll
    for (int f = 0; f < 8; ++f) {
      ut[f] = red[0][f] + red[1][f] + red[2][f] + red[3][f] + bias[f];
      u_t[b * 8 + f] = ut[f];
    }
    float s = 0.f;
#pragma unroll
    for (int f = 0; f < 8; ++f) {
      float t1 = 0.f;
#pragma unroll
      for (int fp = 0; fp < 8; ++fp) t1 += mlp_w1[f * 16 + fp] * ut[fp];
      s += t1 * mlp_w2[f];
    }
    s1[b] = s;
  }
}

__global__ __launch_bounds__(256) void k_s2(const float* __restrict__ api,
                                            const float* __restrict__ mlp_w1,
                                            const float* __restrict__ mlp_b1,
                                            const float* __restrict__ mlp_w2,
                                            const float* __restrict__ mlp_b2,
                                            float* __restrict__ s2) {
  int a = blockIdx.x * 256 + threadIdx.x;
  if (a >= 1000) return;
  float ap[8];
#pragma unroll
  for (int fp = 0; fp < 8; ++fp) ap[fp] = api[fp * 1000 + a];
  float s = mlp_b2[0];
#pragma unroll
  for (int f = 0; f < 8; ++f) {
    float t2 = mlp_b1[f];
#pragma unroll
    for (int fp = 0; fp < 8; ++fp) t2 += mlp_w1[f * 16 + 8 + fp] * ap[fp];
    s += t2 * mlp_w2[f];
  }
  s2[a] = s;
}

__global__ __launch_bounds__(256) void k_cat_f32(const float* __restrict__ u_t,
                                                 const float* __restrict__ api,
                                                 const float* __restrict__ s1,
                                                 const float* __restrict__ s2,
                                                 float* __restrict__ cat_mm) {
  int j = blockIdx.x * 256 + threadIdx.x;
  int b = blockIdx.y;
  if (j >= 2000) return;
  if (j < 1000) {
    float v = 0.f;
#pragma unroll
    for (int f = 0; f < 8; ++f) v += u_t[b * 8 + f] * api[f * 1000 + j];
    cat_mm[b * 2000 + j] = v;
  } else {
    cat_mm[b * 2000 + j] = tanhf(s1[b] + s2[j - 1000]);
  }
}

template<int ACT>
__global__ __launch_bounds__(256) void gemm_tn(const float* __restrict__ A, int lda,
                                               const float* __restrict__ W, int ldw,
                                               const float* __restrict__ bias,
                                               float* __restrict__ C, int ldc,
                                               int M, int N, int K) {
  __shared__ float As[8][33];
  __shared__ float Ws[8][33];
  const int n0 = blockIdx.x * 32, m0 = blockIdx.y * 32;
  const int tid = threadIdx.x;
  const int tx = tid % 16, ty = tid / 16;
  const int ms = tid / 8, ks = tid % 8;
  float acc[2][2] = {{0.f, 0.f}, {0.f, 0.f}};
  for (int k0 = 0; k0 < K; k0 += 8) {
    As[ks][ms] = A[(m0 + ms) * lda + k0 + ks];
    int n = n0 + ms;
    Ws[ks][ms] = (n < N) ? W[n * ldw + k0 + ks] : 0.f;
    __syncthreads();
#pragma unroll
    for (int kk = 0; kk < 8; ++kk) {
      float a0 = As[kk][ty], a1 = As[kk][ty + 16];
      float w0 = Ws[kk][tx], w1 = Ws[kk][tx + 16];
      acc[0][0] = fmaf(a0, w0, acc[0][0]);
      acc[0][1] = fmaf(a0, w1, acc[0][1]);
      acc[1][0] = fmaf(a1, w0, acc[1][0]);
      acc[1][1] = fmaf(a1, w1, acc[1][1]);
    }
    __syncthreads();
  }
#pragma unroll
  for (int i = 0; i < 2; ++i)
#pragma unroll
    for (int j = 0; j < 2; ++j) {
      int m = m0 + ty + 16 * i, n = n0 + tx + 16 * j;
      if (n < N) {
        float v = acc[i][j] + bias[n];
        if (ACT) v = tanhf(v);
        C[m * ldc + n] = v;
      }
    }
}

// ---------------------------------------------------------------------------
extern "C" void kernel_launch(void* const* d_in, const int* in_sizes, int n_in,
                              void* d_out, int out_size, void* d_ws, size_t ws_size,
                              hipStream_t stream) {
  const int*   text_ids  = (const int*)d_in[0];
  const float* emb       = (const float*)d_in[1];
  const float* cw2       = (const float*)d_in[2];
  const float* cb2       = (const float*)d_in[3];
  const float* cw3       = (const float*)d_in[4];
  const float* cb3       = (const float*)d_in[5];
  const float* cw4       = (const float*)d_in[6];
  const float* cb4       = (const float*)d_in[7];
  const float* cw5       = (const float*)d_in[8];
  const float* cb5       = (const float*)d_in[9];
  const float* sc_w      = (const float*)d_in[10];
  const float* sc_b      = (const float*)d_in[11];
  const float* fic_fc_w  = (const float*)d_in[12];
  const float* fic_fc_b  = (const float*)d_in[13];
  const float* api       = (const float*)d_in[14];
  const float* mlp_w1    = (const float*)d_in[15];
  const float* mlp_b1    = (const float*)d_in[16];
  const float* mlp_w2    = (const float*)d_in[17];
  const float* mlp_b2    = (const float*)d_in[18];
  const float* fic_fcl_w = (const float*)d_in[19];
  const float* fic_fcl_b = (const float*)d_in[20];
  const float* fusion_w  = (const float*)d_in[21];
  const float* fusion_b  = (const float*)d_in[22];
  const float* out_w     = (const float*)d_in[23];
  const float* out_b     = (const float*)d_in[24];

  float* ws = (float*)d_ws;
  float* e_buf = ws;                       // 262144 f32
  float* cbias = e_buf + 262144;           // 1024
  // bf16 region (offset 263168*4 B, 16-aligned)
  __hip_bfloat16* bfb       = (__hip_bfloat16*)(cbias + 1024);
  __hip_bfloat16* e_bf      = bfb;                  // 262144 (256x1024)
  __hip_bfloat16* cat_mm_bf = e_bf + 262144;        // 524288 (256x2048)
  __hip_bfloat16* cat_sc_bf = cat_mm_bf + 524288;   // 524288 (256x2048)
  __hip_bfloat16* u_mmf_bf  = cat_sc_bf + 524288;   // 262144 (256x1024)
  __hip_bfloat16* emb_bf    = u_mmf_bf + 262144;    // 6400128 (50001x128)
  __hip_bfloat16* Wc        = emb_bf + 6400128;     // 655360
  __hip_bfloat16* wt_sc     = Wc + 655360;          // 1048576
  __hip_bfloat16* wt_fic    = wt_sc + 1048576;      // 2097152
  __hip_bfloat16* wt_fus    = wt_fic + 2097152;     // 2097152
  __hip_bfloat16* wt_out    = wt_fus + 2097152;     // 1048576
  int* ids_pad = (int*)(wt_out + 1048576);          // 131080 ints
  const size_t need_fast =
      263168UL * 4 + 14919808UL * 2 + 131080UL * 4;  // ~31.4 MB

  if (ws_size >= need_fast) {
    prep_all<<<4096, 256, 0, stream>>>(text_ids, emb, cw2, cw3, cw4, cw5,
                                       cb2, cb3, cb4, cb5, sc_w, fic_fcl_w,
                                       fusion_w, out_w, emb_bf, Wc, cbias,
                                       wt_sc, wt_fic, wt_fus, wt_out, ids_pad);
    conv_mfma<<<1024, 512, 0, stream>>>(emb_bf, ids_pad, Wc, cbias, e_buf, e_bf);
    k_heads<<<256, 256, 0, stream>>>(e_buf, fic_fc_w, fic_fc_b, api, mlp_w1,
                                     mlp_b1, mlp_w2, mlp_b2, cat_mm_bf);
    gemm128_sc_fic<<<dim3(8, 4, 2), 256, 0, stream>>>(e_bf, cat_mm_bf, wt_sc,
                                                      wt_fic, sc_b, fic_fcl_b,
                                                      cat_sc_bf);
    gemm128<0, 1><<<dim3(8, 4), 256, 0, stream>>>(cat_sc_bf, 2048, wt_fus, 2048,
                                                  fusion_b, u_mmf_bf, 1024,
                                                  1000, 2048);
    gemm128<0, 0><<<dim3(8, 4), 256, 0, stream>>>(u_mmf_bf, 1024, wt_out, 1024,
                                                  out_b, d_out, 1000, 1000, 1024);
  } else {
    // f32 fallback (round-0 verified path) — needs zeroed e_buf for atomicMax
    hipMemsetAsync(e_buf, 0, 262144 * sizeof(float), stream);
    float* u_t    = (float*)bfb;            // 2048
    float* s1     = u_t + 2048;             // 256
    float* s2     = s1 + 256;               // 1024
    float* cat_mm = s2 + 1024;              // 512000
    float* cat_sc = cat_mm + 512000;        // 512000
    float* u_mmf  = cat_sc + 512000;        // 256000
    float* wt     = u_mmf + 256000;         // 358400
    transpose_w<<<200, 256, 0, stream>>>(cw2, wt + 0,      200);
    transpose_w<<<300, 256, 0, stream>>>(cw3, wt + 51200,  300);
    transpose_w<<<400, 256, 0, stream>>>(cw4, wt + 128000, 400);
    transpose_w<<<500, 256, 0, stream>>>(cw5, wt + 230400, 500);
    conv_pool<2><<<dim3(16, 256), 256, 0, stream>>>(text_ids, emb, wt + 0,      cb2, e_buf, 0);
    conv_pool<3><<<dim3(16, 256), 256, 0, stream>>>(text_ids, emb, wt + 51200,  cb3, e_buf, 1);
    conv_pool<4><<<dim3(16, 256), 256, 0, stream>>>(text_ids, emb, wt + 128000, cb4, e_buf, 2);
    conv_pool<5><<<dim3(16, 256), 256, 0, stream>>>(text_ids, emb, wt + 230400, cb5, e_buf, 3);
    k_ut_s1<<<256, 256, 0, stream>>>(e_buf, fic_fc_w, fic_fc_b, mlp_w1, mlp_w2, u_t, s1);
    k_s2<<<4, 256, 0, stream>>>(api, mlp_w1, mlp_b1, mlp_w2, mlp_b2, s2);
    k_cat_f32<<<dim3(8, 256), 256, 0, stream>>>(u_t, api, s1, s2, cat_mm);
    gemm_tn<0><<<dim3(32, 8), 256, 0, stream>>>(e_buf, 1024, sc_w, 1024, sc_b,
                                                cat_sc, 2000, 256, 1000, 1024);
    gemm_tn<1><<<dim3(32, 8), 256, 0, stream>>>(cat_mm, 2000, fic_fcl_w, 2000, fic_fcl_b,
                                                cat_sc + 1000, 2000, 256, 1000, 2000);
    gemm_tn<0><<<dim3(32, 8), 256, 0, stream>>>(cat_sc, 2000, fusion_w, 2000, fusion_b,
                                                u_mmf, 1000, 256, 1000, 2000);
    gemm_tn<0><<<dim3(32, 8), 256, 0, stream>>>(u_mmf, 1000, out_w, 1000, out_b,
                                                (float*)d_out, 1000, 256, 1000, 1000);
  }
}

// Round 19
// 224.050 us; speedup vs baseline: 1.1460x; 1.0888x over previous
//
#include <hip/hip_runtime.h>
#include <hip/hip_bf16.h>
#include <math.h>

// Model dims: V=50000, A=1000, E=100, K=256, F=8, B=256, S=512, KS=(2,3,4,5)

typedef __attribute__((ext_vector_type(8))) short short8;
typedef __attribute__((ext_vector_type(4))) short short4v;
typedef __attribute__((ext_vector_type(4))) float f32x4;

__device__ __forceinline__ void gld_lds16(const void* g, void* l) {
  __builtin_amdgcn_global_load_lds(
      (const __attribute__((address_space(1))) unsigned int*)g,
      (__attribute__((address_space(3))) unsigned int*)l, 16, 0, 0);
}

__device__ __forceinline__ short bf16of(float f) {
  union { float f; unsigned u; } x; x.f = f;
  unsigned r = (x.u + 0x7fff + ((x.u >> 16) & 1)) >> 16;   // RNE, matches __float2bfloat16
  return (short)r;
}

// ---------------------------------------------------------------------------
// One grid-stride prep kernel, vec4 (verified R10): emb_bf [50001][128]
// (row 50000 = zeros, cols 100..127 = 0), Wc [1024][640] + cb, 4 epilogue
// weights (bf16, zero-padded), ids_pad [131080] (tail -> 50000 = zero row).
#define O1 6400128   // emb_bf
#define O2 7055488   // Wc
#define O3 8104064   // wt_sc
#define O4 10201216  // wt_fic
#define O5 12298368  // wt_fus
#define O6 13346944  // wt_out
#define OT 13478024
__global__ __launch_bounds__(256) void prep_all(
    const int* __restrict__ text_ids, const float* __restrict__ emb,
    const float* __restrict__ w2, const float* __restrict__ w3,
    const float* __restrict__ w4, const float* __restrict__ w5,
    const float* __restrict__ b2, const float* __restrict__ b3,
    const float* __restrict__ b4, const float* __restrict__ b5,
    const float* __restrict__ sc_w, const float* __restrict__ fic_w,
    const float* __restrict__ fus_w, const float* __restrict__ out_w,
    __hip_bfloat16* __restrict__ emb_bf, __hip_bfloat16* __restrict__ Wc,
    float* __restrict__ cb, __hip_bfloat16* __restrict__ wt_sc,
    __hip_bfloat16* __restrict__ wt_fic, __hip_bfloat16* __restrict__ wt_fus,
    __hip_bfloat16* __restrict__ wt_out, int* __restrict__ ids_pad) {
  for (int v = blockIdx.x * 256 + threadIdx.x; v < OT / 4;
       v += gridDim.x * 256) {
    const int idx = v * 4;
    if (idx < O1) {                       // emb_bf
      const int row = idx >> 7, e = idx & 127;
      float4 f = make_float4(0.f, 0.f, 0.f, 0.f);
      if (row < 50000 && e < 100)          // e in {0,4,..,96}: e+3<=99 valid
        f = *(const float4*)(emb + row * 100 + e);
      *(short4v*)(emb_bf + idx) =
          (short4v){bf16of(f.x), bf16of(f.y), bf16of(f.z), bf16of(f.w)};
    } else if (idx < O2) {                // Wc + cb
      const int t = idx - O1;
      const int n = t / 640, k = t % 640;  // 640%4==0 -> same n, same dh
      const int h = 2 + (n >> 8), kc = n & 255;
      const int dh = k >> 7, e = k & 127;
      const float* w = (h == 2) ? w2 : (h == 3) ? w3 : (h == 4) ? w4 : w5;
      short4v o;
#pragma unroll
      for (int i = 0; i < 4; ++i)
        o[i] = (dh < h && e + i < 100) ? bf16of(w[(kc * 100 + e + i) * h + dh])
                                       : (short)0;
      *(short4v*)(Wc + t) = o;
      if (k == 0) {
        const float* bb = (h == 2) ? b2 : (h == 3) ? b3 : (h == 4) ? b4 : b5;
        cb[n] = bb[kc];
      }
    } else if (idx < O3) {                // sc: [1000][1024] -> [1024][1024]
      const int t = idx - O2;
      const int n = t >> 10, k = t & 1023;
      float4 f = make_float4(0.f, 0.f, 0.f, 0.f);
      if (n < 1000) f = *(const float4*)(sc_w + n * 1024 + k);
      *(short4v*)(wt_sc + t) =
          (short4v){bf16of(f.x), bf16of(f.y), bf16of(f.z), bf16of(f.w)};
    } else if (idx < O4) {                // fic: [1000][2000] -> [1024][2048]
      const int t = idx - O3;
      const int n = t >> 11, k = t & 2047;
      float4 f = make_float4(0.f, 0.f, 0.f, 0.f);
      if (n < 1000 && k < 2000) f = *(const float4*)(fic_w + n * 2000 + k);
      *(short4v*)(wt_fic + t) =
          (short4v){bf16of(f.x), bf16of(f.y), bf16of(f.z), bf16of(f.w)};
    } else if (idx < O5) {                // fus: [1000][2000] -> [1024][2048]
      const int t = idx - O4;
      const int n = t >> 11, k = t & 2047;
      float4 f = make_float4(0.f, 0.f, 0.f, 0.f);
      if (n < 1000 && k < 2000) f = *(const float4*)(fus_w + n * 2000 + k);
      *(short4v*)(wt_fus + t) =
          (short4v){bf16of(f.x), bf16of(f.y), bf16of(f.z), bf16of(f.w)};
    } else if (idx < O6) {                // out: [1000][1000] -> [1024][1024]
      const int t = idx - O5;
      const int n = t >> 10, k = t & 1023;
      float4 f = make_float4(0.f, 0.f, 0.f, 0.f);
      if (n < 1000 && k < 1000) f = *(const float4*)(out_w + n * 1000 + k);
      *(short4v*)(wt_out + t) =
          (short4v){bf16of(f.x), bf16of(f.y), bf16of(f.z), bf16of(f.w)};
    } else {                              // ids_pad
      const int t = idx - O6;
      if (t + 3 < 131072) {
        *(int4*)(ids_pad + t) = *(const int4*)(text_ids + t);
      } else {
#pragma unroll
        for (int i = 0; i < 4; ++i)
          ids_pad[t + i] = (t + i < 131072) ? text_ids[t + i] : 50000;
      }
    }
  }
}

// ---------------------------------------------------------------------------
// Implicit-GEMM conv + bias + relu + maxpool; persistent per-(batch, nb) block.
// R10/R17-VERIFIED 256x256 version (169.9-170.3 us). Structure-family plateau.
__global__ __launch_bounds__(512, 2) void conv_mfma(const __hip_bfloat16* __restrict__ Eb_,
                                                    const int* __restrict__ ids_pad,
                                                    const __hip_bfloat16* __restrict__ Wc_,
                                                    const float* __restrict__ cb,
                                                    float* __restrict__ e_out,
                                                    __hip_bfloat16* __restrict__ e_bf) {
  __shared__ __align__(16) short As[2][256 * 64];  // 64 KB
  __shared__ __align__(16) short Bs[2][256 * 64];  // 64 KB
  __shared__ int ids_s[520];                       // 516 used
  __shared__ float pm_s[8][64];
  const int g = blockIdx.x;
  const int xcd = g & 7, i = g >> 3;
  const int nb = 3 - (i & 3);            // long (nb=3) blocks dispatch first
  const int b = ((i >> 2) << 3) | xcd;   // 0..255; siblings share xcd
  const int N0 = nb << 8;
  const int nt = (2 + nb) * 2;           // K-steps of 64 per subtile: 4/6/8/10
  const int NS = nt * 2;                 // total steps (2 M-subtiles)
  const int tid = threadIdx.x;
  const int lane = tid & 63;
  const int wid = tid >> 6;
  const int wr = wid >> 2, wc = wid & 3;  // 2x4 wave grid; wave tile 128x64
  const short* Eb = (const short*)Eb_;
  const short* Wc = (const short*)Wc_;

  ids_s[tid] = ids_pad[b * 512 + tid];                           // 0..511
  if (tid < 4) ids_s[512 + tid] = ids_pad[b * 512 + 512 + tid];  // 512..515
  __syncthreads();

  f32x4 acc[8][4];
#pragma unroll
  for (int ii = 0; ii < 8; ++ii)
#pragma unroll
    for (int jj = 0; jj < 4; ++jj) acc[ii][jj] = (f32x4){0.f, 0.f, 0.f, 0.f};
  float pm[4] = {-3.0e38f, -3.0e38f, -3.0e38f, -3.0e38f};

  auto STAGE = [&](int buf, int step) {
    const int sub = (step >= nt);
    const int ms = sub ? 256 : 0;
    const int k0 = (step - (sub ? nt : 0)) << 6;
    const int dh = k0 >> 7, e0 = k0 & 127;   // 64-col slab lies in one dh
#pragma unroll
    for (int ii = 0; ii < 4; ++ii) {
      const int c = tid + (ii << 9);         // 0..2047
      const int row = c >> 3, cs = c & 7;
      const int scs = cs ^ (row & 7);
      const int id = ids_s[ms + row + dh];   // lgkm read; keeps vmcnt pure
      gld_lds16(Eb + ((long)id << 7) + e0 + scs * 8, &As[buf][c * 8]);
      gld_lds16(Wc + (long)(N0 + row) * 640 + k0 + scs * 8, &Bs[buf][c * 8]);
    }
  };

  STAGE(0, 0);
  for (int t = 0; t < NS; ++t) {
    if (t + 1 < NS) {
      STAGE((t + 1) & 1, t + 1);
      asm volatile("s_waitcnt vmcnt(8)" ::: "memory");   // stage(t) done only
    } else {
      asm volatile("s_waitcnt vmcnt(0)" ::: "memory");
    }
    __builtin_amdgcn_s_barrier();          // A: stage(t) visible to all waves
    const short* Ab = As[t & 1];
    const short* Bb = Bs[t & 1];
#pragma unroll
    for (int ks = 0; ks < 2; ++ks) {
      const int csq = ks * 4 + (lane >> 4);
      short8 av[8], bv[4];
#pragma unroll
      for (int mf = 0; mf < 8; ++mf) {
        const int row = wr * 128 + mf * 16 + (lane & 15);
        av[mf] = *(const short8*)&Ab[row * 64 + (csq ^ (row & 7)) * 8];
      }
#pragma unroll
      for (int nf = 0; nf < 4; ++nf) {
        const int row = wc * 64 + nf * 16 + (lane & 15);
        bv[nf] = *(const short8*)&Bb[row * 64 + (csq ^ (row & 7)) * 8];
      }
#pragma unroll
      for (int mf = 0; mf < 8; ++mf)
#pragma unroll
        for (int nf = 0; nf < 4; ++nf)
          acc[mf][nf] = __builtin_amdgcn_mfma_f32_16x16x32_bf16(av[mf], bv[nf], acc[mf][nf], 0, 0, 0);
    }
    // Subtile-boundary fold: max is exactly associative; reset acc.
    if (t == nt - 1 || t == NS - 1) {
      const bool masked = (t == NS - 1);   // subtile 1: t_global = 256 + tloc
#pragma unroll
      for (int nf = 0; nf < 4; ++nf) {
#pragma unroll
        for (int mf = 0; mf < 8; ++mf) {
          const int tloc = wr * 128 + mf * 16 + (lane >> 4) * 4;
#pragma unroll
          for (int r = 0; r < 4; ++r) {
            if (!masked || (tloc + r <= 254 - nb))
              pm[nf] = fmaxf(pm[nf], acc[mf][nf][r]);
            acc[mf][nf][r] = 0.f;
          }
        }
      }
    }
    asm volatile("s_waitcnt lgkmcnt(0)" ::: "memory");
    __builtin_amdgcn_s_barrier();          // B: reads done before buf reuse
  }

  // Cross-wr combine in LDS, then bias+relu+store (no atomics).
#pragma unroll
  for (int nf = 0; nf < 4; ++nf) {
    float p = pm[nf];
    p = fmaxf(p, __shfl_xor(p, 16, 64));
    p = fmaxf(p, __shfl_xor(p, 32, 64));
    if ((lane >> 4) == 0) pm_s[wid][nf * 16 + (lane & 15)] = p;
  }
  __syncthreads();
  if (tid < 256) {
    const int wcx = tid >> 6, off = tid & 63;
    const int n = N0 + wcx * 64 + off;
    const float v0 = fmaxf(pm_s[wcx][off], pm_s[4 + wcx][off]);
    const float v = fmaxf(v0 + cb[n], 0.f);  // relu(max+bias) == max(relu)
    e_out[b * 1024 + n] = v;
    e_bf[b * 1024 + n] = __float2bfloat16(v);
  }
}

// ---------------------------------------------------------------------------
// 64x128-tile epilogue GEMM body, BK=128 (R18-verified). 4 waves 2x2, wave
// tile 32x64, 16-chunk involution swizzle, counted vmcnt(12).
template<int ACT, int OUTBF>
__device__ __forceinline__ void gemm128_body(const short* __restrict__ A, int lda,
                                             const short* __restrict__ W, int ldw,
                                             const float* __restrict__ bias,
                                             void* __restrict__ Cv, int ldc,
                                             int N, int K, int cofs, int M0, int N0,
                                             short* As0, short* As1,
                                             short* Bs0, short* Bs1) {
  const int tid = threadIdx.x, lane = tid & 63;
  const int wid = tid >> 6;
  const int wr = wid >> 1, wc = wid & 1;
  short* Asb[2] = {As0, As1};
  short* Bsb[2] = {Bs0, Bs1};

  f32x4 acc[2][4];
#pragma unroll
  for (int i = 0; i < 2; ++i)
#pragma unroll
    for (int j = 0; j < 4; ++j) acc[i][j] = (f32x4){0.f, 0.f, 0.f, 0.f};

  auto STAGE = [&](int buf, int k0) {
#pragma unroll
    for (int i = 0; i < 4; ++i) {          // A: 64 rows x 16 chunks = 1024
      const int c = tid + (i << 8);
      const int row = c >> 4, cs = c & 15;
      const int scs = cs ^ (row & 15);
      gld_lds16(A + (long)(M0 + row) * lda + k0 + scs * 8,
                &Asb[buf][row * 128 + cs * 8]);
    }
#pragma unroll
    for (int i = 0; i < 8; ++i) {          // B: 128 rows x 16 chunks = 2048
      const int c = tid + (i << 8);
      const int row = c >> 4, cs = c & 15;
      const int scs = cs ^ (row & 15);
      gld_lds16(W + (long)(N0 + row) * ldw + k0 + scs * 8,
                &Bsb[buf][row * 128 + cs * 8]);
    }
  };

  const int nt = K >> 7;                   // BK=128 steps
  STAGE(0, 0);
  for (int t = 0; t < nt; ++t) {
    if (t + 1 < nt) {
      STAGE((t + 1) & 1, (t + 1) << 7);
      asm volatile("s_waitcnt vmcnt(12)" ::: "memory");  // stage(t) done only
    } else {
      asm volatile("s_waitcnt vmcnt(0)" ::: "memory");
    }
    __builtin_amdgcn_s_barrier();
    const short* Ab = Asb[t & 1];
    const short* Bb = Bsb[t & 1];
#pragma unroll
    for (int ks = 0; ks < 4; ++ks) {       // 4 K-slices of 32
      const int csq = ks * 4 + (lane >> 4);
      short8 av[2], bv[4];
#pragma unroll
      for (int mf = 0; mf < 2; ++mf) {
        const int row = wr * 32 + mf * 16 + (lane & 15);
        av[mf] = *(const short8*)&Ab[row * 128 + (csq ^ (row & 15)) * 8];
      }
#pragma unroll
      for (int nf = 0; nf < 4; ++nf) {
        const int row = wc * 64 + nf * 16 + (lane & 15);
        bv[nf] = *(const short8*)&Bb[row * 128 + (csq ^ (row & 15)) * 8];
      }
#pragma unroll
      for (int mf = 0; mf < 2; ++mf)
#pragma unroll
        for (int nf = 0; nf < 4; ++nf)
          acc[mf][nf] = __builtin_amdgcn_mfma_f32_16x16x32_bf16(av[mf], bv[nf], acc[mf][nf], 0, 0, 0);
    }
    asm volatile("s_waitcnt lgkmcnt(0)" ::: "memory");
    __builtin_amdgcn_s_barrier();
  }

#pragma unroll
  for (int nf = 0; nf < 4; ++nf) {
    const int n = N0 + wc * 64 + nf * 16 + (lane & 15);
    const float bv = (n < N) ? bias[n] : 0.f;
#pragma unroll
    for (int mf = 0; mf < 2; ++mf) {
      const int m = M0 + wr * 32 + mf * 16 + (lane >> 4) * 4;
#pragma unroll
      for (int r = 0; r < 4; ++r) {
        float v = acc[mf][nf][r] + bv;
        if (ACT) v = tanhf(v);
        if (n < N) {
          if (OUTBF)
            ((__hip_bfloat16*)Cv)[(long)(m + r) * ldc + cofs + n] = __float2bfloat16(v);
          else
            ((float*)Cv)[(long)(m + r) * ldc + cofs + n] = v;
        }
      }
    }
  }
}

// ---------------------------------------------------------------------------
// 64x64-tile epilogue GEMM body, BK=256 (R19): halves the serial K-step count
// of the K=2048 latency-bound GEMMs (16->8 steps). 4 waves 2x2, wave tile
// 32x32, LDS 2x64 KB dbuf, 32-chunk involution swizzle (cs^(row&31); residual
// 2-way aliasing free per m136), counted vmcnt(16). K order = ascending
// 32-element slices (same as BK=128) -> bit-identical results.
template<int ACT, int OUTBF>
__device__ __forceinline__ void gemm256_body(const short* __restrict__ A, int lda,
                                             const short* __restrict__ W, int ldw,
                                             const float* __restrict__ bias,
                                             void* __restrict__ Cv, int ldc,
                                             int N, int K, int cofs, int M0, int N0,
                                             short* As0, short* As1,
                                             short* Bs0, short* Bs1) {
  const int tid = threadIdx.x, lane = tid & 63;
  const int wid = tid >> 6;
  const int wr = wid >> 1, wc = wid & 1;   // 2x2 wave grid; wave tile 32x32
  short* Asb[2] = {As0, As1};
  short* Bsb[2] = {Bs0, Bs1};

  f32x4 acc[2][2];
#pragma unroll
  for (int i = 0; i < 2; ++i)
#pragma unroll
    for (int j = 0; j < 2; ++j) acc[i][j] = (f32x4){0.f, 0.f, 0.f, 0.f};

  auto STAGE = [&](int buf, int k0) {
#pragma unroll
    for (int i = 0; i < 8; ++i) {          // A: 64 rows x 32 chunks = 2048
      const int c = tid + (i << 8);
      const int row = c >> 5, cs = c & 31;
      const int scs = cs ^ (row & 31);
      gld_lds16(A + (long)(M0 + row) * lda + k0 + scs * 8,
                &Asb[buf][row * 256 + cs * 8]);
    }
#pragma unroll
    for (int i = 0; i < 8; ++i) {          // B: 64 rows x 32 chunks = 2048
      const int c = tid + (i << 8);
      const int row = c >> 5, cs = c & 31;
      const int scs = cs ^ (row & 31);
      gld_lds16(W + (long)(N0 + row) * ldw + k0 + scs * 8,
                &Bsb[buf][row * 256 + cs * 8]);
    }
  };

  const int nt = K >> 8;                   // BK=256 steps
  STAGE(0, 0);
  for (int t = 0; t < nt; ++t) {
    if (t + 1 < nt) {
      STAGE((t + 1) & 1, (t + 1) << 8);
      asm volatile("s_waitcnt vmcnt(16)" ::: "memory");  // stage(t) done only
    } else {
      asm volatile("s_waitcnt vmcnt(0)" ::: "memory");
    }
    __builtin_amdgcn_s_barrier();
    const short* Ab = Asb[t & 1];
    const short* Bb = Bsb[t & 1];
#pragma unroll
    for (int ks = 0; ks < 8; ++ks) {       // 8 K-slices of 32
      const int csq = ks * 4 + (lane >> 4);
      short8 av[2], bv[2];
#pragma unroll
      for (int mf = 0; mf < 2; ++mf) {
        const int row = wr * 32 + mf * 16 + (lane & 15);
        av[mf] = *(const short8*)&Ab[row * 256 + (csq ^ (row & 31)) * 8];
      }
#pragma unroll
      for (int nf = 0; nf < 2; ++nf) {
        const int row = wc * 32 + nf * 16 + (lane & 15);
        bv[nf] = *(const short8*)&Bb[row * 256 + (csq ^ (row & 31)) * 8];
      }
#pragma unroll
      for (int mf = 0; mf < 2; ++mf)
#pragma unroll
        for (int nf = 0; nf < 2; ++nf)
          acc[mf][nf] = __builtin_amdgcn_mfma_f32_16x16x32_bf16(av[mf], bv[nf], acc[mf][nf], 0, 0, 0);
    }
    asm volatile("s_waitcnt lgkmcnt(0)" ::: "memory");
    __builtin_amdgcn_s_barrier();
  }

#pragma unroll
  for (int nf = 0; nf < 2; ++nf) {
    const int n = N0 + wc * 32 + nf * 16 + (lane & 15);
    const float bv = (n < N) ? bias[n] : 0.f;
#pragma unroll
    for (int mf = 0; mf < 2; ++mf) {
      const int m = M0 + wr * 32 + mf * 16 + (lane >> 4) * 4;
#pragma unroll
      for (int r = 0; r < 4; ++r) {
        float v = acc[mf][nf][r] + bv;
        if (ACT) v = tanhf(v);
        if (n < N) {
          if (OUTBF)
            ((__hip_bfloat16*)Cv)[(long)(m + r) * ldc + cofs + n] = __float2bfloat16(v);
          else
            ((float*)Cv)[(long)(m + r) * ldc + cofs + n] = v;
        }
      }
    }
  }
}

template<int ACT, int OUTBF>
__global__ __launch_bounds__(256) void gemm128(const __hip_bfloat16* __restrict__ A_,
                                               int lda,
                                               const __hip_bfloat16* __restrict__ W_,
                                               int ldw,
                                               const float* __restrict__ bias,
                                               void* __restrict__ Cv, int ldc,
                                               int N, int K) {
  __shared__ __align__(16) short As[2][64 * 128];   // 32 KB
  __shared__ __align__(16) short Bs[2][128 * 128];  // 64 KB
  gemm128_body<ACT, OUTBF>((const short*)A_, lda, (const short*)W_, ldw, bias,
                           Cv, ldc, N, K, 0, blockIdx.y << 6, blockIdx.x << 7,
                           As[0], As[1], Bs[0], Bs[1]);
}

template<int ACT, int OUTBF>
__global__ __launch_bounds__(256) void gemm256(const __hip_bfloat16* __restrict__ A_,
                                               int lda,
                                               const __hip_bfloat16* __restrict__ W_,
                                               int ldw,
                                               const float* __restrict__ bias,
                                               void* __restrict__ Cv, int ldc,
                                               int N, int K) {
  __shared__ __align__(16) short As[2][64 * 256];   // 64 KB
  __shared__ __align__(16) short Bs[2][64 * 256];   // 64 KB
  gemm256_body<ACT, OUTBF>((const short*)A_, lda, (const short*)W_, ldw, bias,
                           Cv, ldc, N, K, 0, blockIdx.y << 6, blockIdx.x << 6,
                           As[0], As[1], Bs[0], Bs[1]);
}

// Fused u_sc (z=0: BK=128 body, K=1024, 128-col tiles, bx<8) +
// u_fic (z=1: BK=256 body, K=2048, 64-col tiles, bx<16) -> cat_sc_bf.
// Shared LDS: two 64 KB buffers; gemm128_body uses A<=32KB of P, B<=64KB of Q.
__global__ __launch_bounds__(256) void gemm_sc_fic(
    const __hip_bfloat16* __restrict__ e_bf,
    const __hip_bfloat16* __restrict__ cat_mm_bf,
    const __hip_bfloat16* __restrict__ wt_sc,
    const __hip_bfloat16* __restrict__ wt_fic,
    const float* __restrict__ sc_b, const float* __restrict__ fic_b,
    __hip_bfloat16* __restrict__ cat_sc) {
  __shared__ __align__(16) short P[2][64 * 256];    // 64 KB
  __shared__ __align__(16) short Q[2][64 * 256];    // 64 KB
  const int z = blockIdx.z;
  if (z == 0) {
    if (blockIdx.x >= 8) return;           // 8 x 128-col tiles cover N=1000
    gemm128_body<0, 1>((const short*)e_bf, 1024, (const short*)wt_sc, 1024,
                       sc_b, cat_sc, 2048, 1000, 1024, 0, blockIdx.y << 6,
                       blockIdx.x << 7, P[0], P[1], Q[0], Q[1]);
  } else {
    gemm256_body<1, 1>((const short*)cat_mm_bf, 2048, (const short*)wt_fic,
                       2048, fic_b, cat_sc, 2048, 1000, 2048, 1000,
                       blockIdx.y << 6, blockIdx.x << 6, P[0], P[1], Q[0], Q[1]);
  }
}

// ---------------------------------------------------------------------------
// Fused heads: per block b -- u_t (wave reduce), s1, then cat_mm_bf[b,:1000]=
// u_mm, [1000:2000]=u_mlp (s2 recomputed per api column), [2000:2048]=0.
__global__ __launch_bounds__(256) void k_heads(const float* __restrict__ e_buf,
                                               const float* __restrict__ W,
                                               const float* __restrict__ bias,
                                               const float* __restrict__ api,
                                               const float* __restrict__ mlp_w1,
                                               const float* __restrict__ mlp_b1,
                                               const float* __restrict__ mlp_w2,
                                               const float* __restrict__ mlp_b2,
                                               __hip_bfloat16* __restrict__ cat) {
  const int b = blockIdx.x, tid = threadIdx.x;
  float4 a = *(const float4*)(e_buf + b * 1024 + tid * 4);
  float acc[8];
#pragma unroll
  for (int f = 0; f < 8; ++f) {
    float4 w = *(const float4*)(W + f * 1024 + tid * 4);
    acc[f] = a.x * w.x + a.y * w.y + a.z * w.z + a.w * w.w;
  }
#pragma unroll
  for (int f = 0; f < 8; ++f)
    for (int off = 32; off; off >>= 1) acc[f] += __shfl_down(acc[f], off);
  __shared__ float red[4][8];
  __shared__ float ut_s[8];
  __shared__ float s1_s;
  if ((tid & 63) == 0) {
#pragma unroll
    for (int f = 0; f < 8; ++f) red[tid >> 6][f] = acc[f];
  }
  __syncthreads();
  if (tid == 0) {
    float s = 0.f;
#pragma unroll
    for (int f = 0; f < 8; ++f)
      ut_s[f] = red[0][f] + red[1][f] + red[2][f] + red[3][f] + bias[f];
#pragma unroll
    for (int f = 0; f < 8; ++f) {
      float t1 = 0.f;
#pragma unroll
      for (int fp = 0; fp < 8; ++fp) t1 += mlp_w1[f * 16 + fp] * ut_s[fp];
      s += t1 * mlp_w2[f];
    }
    s1_s = s;
  }
  __syncthreads();
  const float s1v = s1_s;
#pragma unroll
  for (int i = 0; i < 4; ++i) {
    const int j = tid + i * 256;           // 0..1023
    if (j < 1000) {
      float ap[8];
#pragma unroll
      for (int fp = 0; fp < 8; ++fp) ap[fp] = api[fp * 1000 + j];
      float umm = 0.f;
#pragma unroll
      for (int f = 0; f < 8; ++f) umm += ut_s[f] * ap[f];
      float s2 = mlp_b2[0];
#pragma unroll
      for (int f = 0; f < 8; ++f) {
        float t2 = mlp_b1[f];
#pragma unroll
        for (int fp = 0; fp < 8; ++fp) t2 += mlp_w1[f * 16 + 8 + fp] * ap[fp];
        s2 += t2 * mlp_w2[f];
      }
      cat[b * 2048 + j] = __float2bfloat16(umm);
      cat[b * 2048 + 1000 + j] = __float2bfloat16(tanhf(s1v + s2));
    }
  }
  if (tid < 48) cat[b * 2048 + 2000 + tid] = __float2bfloat16(0.f);
}

// ---------------------------------------------------------------------------
// FALLBACK (round-0 f32 path) — used only if ws_size is too small.
__global__ __launch_bounds__(256) void transpose_w(const float* __restrict__ w,
                                                   float* __restrict__ wt, int EH) {
  int idx = blockIdx.x * 256 + threadIdx.x;
  if (idx >= 256 * EH) return;
  int k = idx / EH, r = idx % EH;
  wt[r * 256 + k] = w[idx];
}

template<int H>
__global__ __launch_bounds__(256) void conv_pool(const int* __restrict__ ids,
                                                 const float* __restrict__ emb,
                                                 const float* __restrict__ wt,
                                                 const float* __restrict__ cbias,
                                                 float* __restrict__ e_out,
                                                 int hidx) {
  const int b = blockIdx.y;
  const int t0 = blockIdx.x * 32;
  const int L = 512 - H + 1;
  __shared__ float4 xs4[100][10];
  float* xs = (float*)xs4;
  const int tid = threadIdx.x;
  const int WIN = 32 + H - 1;
  for (int idx = tid; idx < WIN * 25; idx += 256) {
    int p = idx / 25, c = idx % 25;
    int s = t0 + p;
    float4 v = make_float4(0.f, 0.f, 0.f, 0.f);
    if (s < 512) {
      int id = ids[b * 512 + s];
      v = *(const float4*)(emb + (long)id * 100 + c * 4);
    }
    xs[(4 * c + 0) * 40 + p] = v.x;
    xs[(4 * c + 1) * 40 + p] = v.y;
    xs[(4 * c + 2) * 40 + p] = v.z;
    xs[(4 * c + 3) * 40 + p] = v.w;
  }
  __syncthreads();
  const int k = tid;
  float acc[32];
#pragma unroll
  for (int t = 0; t < 32; ++t) acc[t] = 0.f;
  const float* wk = wt + k;
  for (int e = 0; e < 100; ++e) {
    float win[36];
#pragma unroll
    for (int i = 0; i < 9; ++i)
      *(float4*)&win[i * 4] = *(const float4*)&xs[e * 40 + i * 4];
    float wr[H];
#pragma unroll
    for (int dh = 0; dh < H; ++dh) wr[dh] = wk[(e * H + dh) * 256];
#pragma unroll
    for (int t = 0; t < 32; ++t) {
      float s = acc[t];
#pragma unroll
      for (int dh = 0; dh < H; ++dh) s = fmaf(wr[dh], win[t + dh], s);
      acc[t] = s;
    }
  }
  const float bk = cbias[k];
  float m = 0.f;
#pragma unroll
  for (int t = 0; t < 32; ++t) {
    if (t0 + t < L) m = fmaxf(m, fmaxf(acc[t] + bk, 0.f));
  }
  atomicMax((int*)&e_out[b * 1024 + hidx * 256 + k], __float_as_int(m));
}

__global__ __launch_bounds__(256) void k_ut_s1(const float* __restrict__ e_buf,
                                               const float* __restrict__ W,
                                               const float* __restrict__ bias,
                                               const float* __restrict__ mlp_w1,
                                               const float* __restrict__ mlp_w2,
                                               float* __restrict__ u_t,
                                               float* __restrict__ s1) {
  const int b = blockIdx.x, tid = threadIdx.x;
  float4 a = *(const float4*)(e_buf + b * 1024 + tid * 4);
  float acc[8];
#pragma unroll
  for (int f = 0; f < 8; ++f) {
    float4 w = *(const float4*)(W + f * 1024 + tid * 4);
    acc[f] = a.x * w.x + a.y * w.y + a.z * w.z + a.w * w.w;
  }
#pragma unroll
  for (int f = 0; f < 8; ++f)
    for (int off = 32; off; off >>= 1) acc[f] += __shfl_down(acc[f], off);
  __shared__ float red[4][8];
  if ((tid & 63) == 0) {
#pragma unroll
    for (int f = 0; f < 8; ++f) red[tid >> 6][f] = acc[f];
  }
  __syncthreads();
  if (tid == 0) {
    float ut[8];
#pragma unroll
    for (int f = 0; f < 8; ++f) {
      ut[f] = red[0][f] + red[1][f] + red[2][f] + red[3][f] + bias[f];
      u_t[b * 8 + f] = ut[f];
    }
    float s = 0.f;
#pragma unroll
    for (int f = 0; f < 8; ++f) {
      float t1 = 0.f;
#pragma unroll
      for (int fp = 0; fp < 8; ++fp) t1 += mlp_w1[f * 16 + fp] * ut[fp];
      s += t1 * mlp_w2[f];
    }
    s1[b] = s;
  }
}

__global__ __launch_bounds__(256) void k_s2(const float* __restrict__ api,
                                            const float* __restrict__ mlp_w1,
                                            const float* __restrict__ mlp_b1,
                                            const float* __restrict__ mlp_w2,
                                            const float* __restrict__ mlp_b2,
                                            float* __restrict__ s2) {
  int a = blockIdx.x * 256 + threadIdx.x;
  if (a >= 1000) return;
  float ap[8];
#pragma unroll
  for (int fp = 0; fp < 8; ++fp) ap[fp] = api[fp * 1000 + a];
  float s = mlp_b2[0];
#pragma unroll
  for (int f = 0; f < 8; ++f) {
    float t2 = mlp_b1[f];
#pragma unroll
    for (int fp = 0; fp < 8; ++fp) t2 += mlp_w1[f * 16 + 8 + fp] * ap[fp];
    s += t2 * mlp_w2[f];
  }
  s2[a] = s;
}

__global__ __launch_bounds__(256) void k_cat_f32(const float* __restrict__ u_t,
                                                 const float* __restrict__ api,
                                                 const float* __restrict__ s1,
                                                 const float* __restrict__ s2,
                                                 float* __restrict__ cat_mm) {
  int j = blockIdx.x * 256 + threadIdx.x;
  int b = blockIdx.y;
  if (j >= 2000) return;
  if (j < 1000) {
    float v = 0.f;
#pragma unroll
    for (int f = 0; f < 8; ++f) v += u_t[b * 8 + f] * api[f * 1000 + j];
    cat_mm[b * 2000 + j] = v;
  } else {
    cat_mm[b * 2000 + j] = tanhf(s1[b] + s2[j - 1000]);
  }
}

template<int ACT>
__global__ __launch_bounds__(256) void gemm_tn(const float* __restrict__ A, int lda,
                                               const float* __restrict__ W, int ldw,
                                               const float* __restrict__ bias,
                                               float* __restrict__ C, int ldc,
                                               int M, int N, int K) {
  __shared__ float As[8][33];
  __shared__ float Ws[8][33];
  const int n0 = blockIdx.x * 32, m0 = blockIdx.y * 32;
  const int tid = threadIdx.x;
  const int tx = tid % 16, ty = tid / 16;
  const int ms = tid / 8, ks = tid % 8;
  float acc[2][2] = {{0.f, 0.f}, {0.f, 0.f}};
  for (int k0 = 0; k0 < K; k0 += 8) {
    As[ks][ms] = A[(m0 + ms) * lda + k0 + ks];
    int n = n0 + ms;
    Ws[ks][ms] = (n < N) ? W[n * ldw + k0 + ks] : 0.f;
    __syncthreads();
#pragma unroll
    for (int kk = 0; kk < 8; ++kk) {
      float a0 = As[kk][ty], a1 = As[kk][ty + 16];
      float w0 = Ws[kk][tx], w1 = Ws[kk][tx + 16];
      acc[0][0] = fmaf(a0, w0, acc[0][0]);
      acc[0][1] = fmaf(a0, w1, acc[0][1]);
      acc[1][0] = fmaf(a1, w0, acc[1][0]);
      acc[1][1] = fmaf(a1, w1, acc[1][1]);
    }
    __syncthreads();
  }
#pragma unroll
  for (int i = 0; i < 2; ++i)
#pragma unroll
    for (int j = 0; j < 2; ++j) {
      int m = m0 + ty + 16 * i, n = n0 + tx + 16 * j;
      if (n < N) {
        float v = acc[i][j] + bias[n];
        if (ACT) v = tanhf(v);
        C[m * ldc + n] = v;
      }
    }
}

// ---------------------------------------------------------------------------
extern "C" void kernel_launch(void* const* d_in, const int* in_sizes, int n_in,
                              void* d_out, int out_size, void* d_ws, size_t ws_size,
                              hipStream_t stream) {
  const int*   text_ids  = (const int*)d_in[0];
  const float* emb       = (const float*)d_in[1];
  const float* cw2       = (const float*)d_in[2];
  const float* cb2       = (const float*)d_in[3];
  const float* cw3       = (const float*)d_in[4];
  const float* cb3       = (const float*)d_in[5];
  const float* cw4       = (const float*)d_in[6];
  const float* cb4       = (const float*)d_in[7];
  const float* cw5       = (const float*)d_in[8];
  const float* cb5       = (const float*)d_in[9];
  const float* sc_w      = (const float*)d_in[10];
  const float* sc_b      = (const float*)d_in[11];
  const float* fic_fc_w  = (const float*)d_in[12];
  const float* fic_fc_b  = (const float*)d_in[13];
  const float* api       = (const float*)d_in[14];
  const float* mlp_w1    = (const float*)d_in[15];
  const float* mlp_b1    = (const float*)d_in[16];
  const float* mlp_w2    = (const float*)d_in[17];
  const float* mlp_b2    = (const float*)d_in[18];
  const float* fic_fcl_w = (const float*)d_in[19];
  const float* fic_fcl_b = (const float*)d_in[20];
  const float* fusion_w  = (const float*)d_in[21];
  const float* fusion_b  = (const float*)d_in[22];
  const float* out_w     = (const float*)d_in[23];
  const float* out_b     = (const float*)d_in[24];

  float* ws = (float*)d_ws;
  float* e_buf = ws;                       // 262144 f32
  float* cbias = e_buf + 262144;           // 1024
  // bf16 region (offset 263168*4 B, 16-aligned)
  __hip_bfloat16* bfb       = (__hip_bfloat16*)(cbias + 1024);
  __hip_bfloat16* e_bf      = bfb;                  // 262144 (256x1024)
  __hip_bfloat16* cat_mm_bf = e_bf + 262144;        // 524288 (256x2048)
  __hip_bfloat16* cat_sc_bf = cat_mm_bf + 524288;   // 524288 (256x2048)
  __hip_bfloat16* u_mmf_bf  = cat_sc_bf + 524288;   // 262144 (256x1024)
  __hip_bfloat16* emb_bf    = u_mmf_bf + 262144;    // 6400128 (50001x128)
  __hip_bfloat16* Wc        = emb_bf + 6400128;     // 655360
  __hip_bfloat16* wt_sc     = Wc + 655360;          // 1048576
  __hip_bfloat16* wt_fic    = wt_sc + 1048576;      // 2097152
  __hip_bfloat16* wt_fus    = wt_fic + 2097152;     // 2097152
  __hip_bfloat16* wt_out    = wt_fus + 2097152;     // 1048576
  int* ids_pad = (int*)(wt_out + 1048576);          // 131080 ints
  const size_t need_fast =
      263168UL * 4 + 14919808UL * 2 + 131080UL * 4;  // ~31.4 MB

  if (ws_size >= need_fast) {
    prep_all<<<4096, 256, 0, stream>>>(text_ids, emb, cw2, cw3, cw4, cw5,
                                       cb2, cb3, cb4, cb5, sc_w, fic_fcl_w,
                                       fusion_w, out_w, emb_bf, Wc, cbias,
                                       wt_sc, wt_fic, wt_fus, wt_out, ids_pad);
    conv_mfma<<<1024, 512, 0, stream>>>(emb_bf, ids_pad, Wc, cbias, e_buf, e_bf);
    k_heads<<<256, 256, 0, stream>>>(e_buf, fic_fc_w, fic_fc_b, api, mlp_w1,
                                     mlp_b1, mlp_w2, mlp_b2, cat_mm_bf);
    gemm_sc_fic<<<dim3(16, 4, 2), 256, 0, stream>>>(e_bf, cat_mm_bf, wt_sc,
                                                    wt_fic, sc_b, fic_fcl_b,
                                                    cat_sc_bf);
    gemm256<0, 1><<<dim3(16, 4), 256, 0, stream>>>(cat_sc_bf, 2048, wt_fus, 2048,
                                                   fusion_b, u_mmf_bf, 1024,
                                                   1000, 2048);
    gemm128<0, 0><<<dim3(8, 4), 256, 0, stream>>>(u_mmf_bf, 1024, wt_out, 1024,
                                                  out_b, d_out, 1000, 1000, 1024);
  } else {
    // f32 fallback (round-0 verified path) — needs zeroed e_buf for atomicMax
    hipMemsetAsync(e_buf, 0, 262144 * sizeof(float), stream);
    float* u_t    = (float*)bfb;            // 2048
    float* s1     = u_t + 2048;             // 256
    float* s2     = s1 + 256;               // 1024
    float* cat_mm = s2 + 1024;              // 512000
    float* cat_sc = cat_mm + 512000;        // 512000
    float* u_mmf  = cat_sc + 512000;        // 256000
    float* wt     = u_mmf + 256000;         // 358400
    transpose_w<<<200, 256, 0, stream>>>(cw2, wt + 0,      200);
    transpose_w<<<300, 256, 0, stream>>>(cw3, wt + 51200,  300);
    transpose_w<<<400, 256, 0, stream>>>(cw4, wt + 128000, 400);
    transpose_w<<<500, 256, 0, stream>>>(cw5, wt + 230400, 500);
    conv_pool<2><<<dim3(16, 256), 256, 0, stream>>>(text_ids, emb, wt + 0,      cb2, e_buf, 0);
    conv_pool<3><<<dim3(16, 256), 256, 0, stream>>>(text_ids, emb, wt + 51200,  cb3, e_buf, 1);
    conv_pool<4><<<dim3(16, 256), 256, 0, stream>>>(text_ids, emb, wt + 128000, cb4, e_buf, 2);
    conv_pool<5><<<dim3(16, 256), 256, 0, stream>>>(text_ids, emb, wt + 230400, cb5, e_buf, 3);
    k_ut_s1<<<256, 256, 0, stream>>>(e_buf, fic_fc_w, fic_fc_b, mlp_w1, mlp_w2, u_t, s1);
    k_s2<<<4, 256, 0, stream>>>(api, mlp_w1, mlp_b1, mlp_w2, mlp_b2, s2);
    k_cat_f32<<<dim3(8, 256), 256, 0, stream>>>(u_t, api, s1, s2, cat_mm);
    gemm_tn<0><<<dim3(32, 8), 256, 0, stream>>>(e_buf, 1024, sc_w, 1024, sc_b,
                                                cat_sc, 2000, 256, 1000, 1024);
    gemm_tn<1><<<dim3(32, 8), 256, 0, stream>>>(cat_mm, 2000, fic_fcl_w, 2000, fic_fcl_b,
                                                cat_sc + 1000, 2000, 256, 1000, 2000);
    gemm_tn<0><<<dim3(32, 8), 256, 0, stream>>>(cat_sc, 2000, fusion_w, 2000, fusion_b,
                                                u_mmf, 1000, 256, 1000, 2000);
    gemm_tn<0><<<dim3(32, 8), 256, 0, stream>>>(u_mmf, 1000, out_w, 1000, out_b,
                                                (float*)d_out, 1000, 256, 1000, 1000);
  }
}

// Round 20
// 207.081 us; speedup vs baseline: 1.2399x; 1.0819x over previous
//
#include <hip/hip_runtime.h>
#include <hip/hip_bf16.h>
#include <math.h>

// Model dims: V=50000, A=1000, E=100, K=256, F=8, B=256, S=512, KS=(2,3,4,5)

typedef __attribute__((ext_vector_type(8))) short short8;
typedef __attribute__((ext_vector_type(4))) short short4v;
typedef __attribute__((ext_vector_type(4))) float f32x4;

__device__ __forceinline__ void gld_lds16(const void* g, void* l) {
  __builtin_amdgcn_global_load_lds(
      (const __attribute__((address_space(1))) unsigned int*)g,
      (__attribute__((address_space(3))) unsigned int*)l, 16, 0, 0);
}

__device__ __forceinline__ short bf16of(float f) {
  union { float f; unsigned u; } x; x.f = f;
  unsigned r = (x.u + 0x7fff + ((x.u >> 16) & 1)) >> 16;   // RNE, matches __float2bfloat16
  return (short)r;
}

// ---------------------------------------------------------------------------
// One grid-stride prep kernel, vec4 (verified R10): emb_bf [50001][128]
// (row 50000 = zeros, cols 100..127 = 0), Wc [1024][640] + cb, 4 epilogue
// weights (bf16, zero-padded), ids_pad [131080] (tail -> 50000 = zero row).
#define O1 6400128   // emb_bf
#define O2 7055488   // Wc
#define O3 8104064   // wt_sc
#define O4 10201216  // wt_fic
#define O5 12298368  // wt_fus
#define O6 13346944  // wt_out
#define OT 13478024
__global__ __launch_bounds__(256) void prep_all(
    const int* __restrict__ text_ids, const float* __restrict__ emb,
    const float* __restrict__ w2, const float* __restrict__ w3,
    const float* __restrict__ w4, const float* __restrict__ w5,
    const float* __restrict__ b2, const float* __restrict__ b3,
    const float* __restrict__ b4, const float* __restrict__ b5,
    const float* __restrict__ sc_w, const float* __restrict__ fic_w,
    const float* __restrict__ fus_w, const float* __restrict__ out_w,
    __hip_bfloat16* __restrict__ emb_bf, __hip_bfloat16* __restrict__ Wc,
    float* __restrict__ cb, __hip_bfloat16* __restrict__ wt_sc,
    __hip_bfloat16* __restrict__ wt_fic, __hip_bfloat16* __restrict__ wt_fus,
    __hip_bfloat16* __restrict__ wt_out, int* __restrict__ ids_pad) {
  for (int v = blockIdx.x * 256 + threadIdx.x; v < OT / 4;
       v += gridDim.x * 256) {
    const int idx = v * 4;
    if (idx < O1) {                       // emb_bf
      const int row = idx >> 7, e = idx & 127;
      float4 f = make_float4(0.f, 0.f, 0.f, 0.f);
      if (row < 50000 && e < 100)          // e in {0,4,..,96}: e+3<=99 valid
        f = *(const float4*)(emb + row * 100 + e);
      *(short4v*)(emb_bf + idx) =
          (short4v){bf16of(f.x), bf16of(f.y), bf16of(f.z), bf16of(f.w)};
    } else if (idx < O2) {                // Wc + cb
      const int t = idx - O1;
      const int n = t / 640, k = t % 640;  // 640%4==0 -> same n, same dh
      const int h = 2 + (n >> 8), kc = n & 255;
      const int dh = k >> 7, e = k & 127;
      const float* w = (h == 2) ? w2 : (h == 3) ? w3 : (h == 4) ? w4 : w5;
      short4v o;
#pragma unroll
      for (int i = 0; i < 4; ++i)
        o[i] = (dh < h && e + i < 100) ? bf16of(w[(kc * 100 + e + i) * h + dh])
                                       : (short)0;
      *(short4v*)(Wc + t) = o;
      if (k == 0) {
        const float* bb = (h == 2) ? b2 : (h == 3) ? b3 : (h == 4) ? b4 : b5;
        cb[n] = bb[kc];
      }
    } else if (idx < O3) {                // sc: [1000][1024] -> [1024][1024]
      const int t = idx - O2;
      const int n = t >> 10, k = t & 1023;
      float4 f = make_float4(0.f, 0.f, 0.f, 0.f);
      if (n < 1000) f = *(const float4*)(sc_w + n * 1024 + k);
      *(short4v*)(wt_sc + t) =
          (short4v){bf16of(f.x), bf16of(f.y), bf16of(f.z), bf16of(f.w)};
    } else if (idx < O4) {                // fic: [1000][2000] -> [1024][2048]
      const int t = idx - O3;
      const int n = t >> 11, k = t & 2047;
      float4 f = make_float4(0.f, 0.f, 0.f, 0.f);
      if (n < 1000 && k < 2000) f = *(const float4*)(fic_w + n * 2000 + k);
      *(short4v*)(wt_fic + t) =
          (short4v){bf16of(f.x), bf16of(f.y), bf16of(f.z), bf16of(f.w)};
    } else if (idx < O5) {                // fus: [1000][2000] -> [1024][2048]
      const int t = idx - O4;
      const int n = t >> 11, k = t & 2047;
      float4 f = make_float4(0.f, 0.f, 0.f, 0.f);
      if (n < 1000 && k < 2000) f = *(const float4*)(fus_w + n * 2000 + k);
      *(short4v*)(wt_fus + t) =
          (short4v){bf16of(f.x), bf16of(f.y), bf16of(f.z), bf16of(f.w)};
    } else if (idx < O6) {                // out: [1000][1000] -> [1024][1024]
      const int t = idx - O5;
      const int n = t >> 10, k = t & 1023;
      float4 f = make_float4(0.f, 0.f, 0.f, 0.f);
      if (n < 1000 && k < 1000) f = *(const float4*)(out_w + n * 1000 + k);
      *(short4v*)(wt_out + t) =
          (short4v){bf16of(f.x), bf16of(f.y), bf16of(f.z), bf16of(f.w)};
    } else {                              // ids_pad
      const int t = idx - O6;
      if (t + 3 < 131072) {
        *(int4*)(ids_pad + t) = *(const int4*)(text_ids + t);
      } else {
#pragma unroll
        for (int i = 0; i < 4; ++i)
          ids_pad[t + i] = (t + i < 131072) ? text_ids[t + i] : 50000;
      }
    }
  }
}

// ---------------------------------------------------------------------------
// Implicit-GEMM conv + bias + relu + maxpool; persistent per-(batch, nb) block.
// R10/R17-VERIFIED 256x256 version (169.9-170.3 us). Structure-family plateau.
__global__ __launch_bounds__(512, 2) void conv_mfma(const __hip_bfloat16* __restrict__ Eb_,
                                                    const int* __restrict__ ids_pad,
                                                    const __hip_bfloat16* __restrict__ Wc_,
                                                    const float* __restrict__ cb,
                                                    float* __restrict__ e_out,
                                                    __hip_bfloat16* __restrict__ e_bf) {
  __shared__ __align__(16) short As[2][256 * 64];  // 64 KB
  __shared__ __align__(16) short Bs[2][256 * 64];  // 64 KB
  __shared__ int ids_s[520];                       // 516 used
  __shared__ float pm_s[8][64];
  const int g = blockIdx.x;
  const int xcd = g & 7, i = g >> 3;
  const int nb = 3 - (i & 3);            // long (nb=3) blocks dispatch first
  const int b = ((i >> 2) << 3) | xcd;   // 0..255; siblings share xcd
  const int N0 = nb << 8;
  const int nt = (2 + nb) * 2;           // K-steps of 64 per subtile: 4/6/8/10
  const int NS = nt * 2;                 // total steps (2 M-subtiles)
  const int tid = threadIdx.x;
  const int lane = tid & 63;
  const int wid = tid >> 6;
  const int wr = wid >> 2, wc = wid & 3;  // 2x4 wave grid; wave tile 128x64
  const short* Eb = (const short*)Eb_;
  const short* Wc = (const short*)Wc_;

  ids_s[tid] = ids_pad[b * 512 + tid];                           // 0..511
  if (tid < 4) ids_s[512 + tid] = ids_pad[b * 512 + 512 + tid];  // 512..515
  __syncthreads();

  f32x4 acc[8][4];
#pragma unroll
  for (int ii = 0; ii < 8; ++ii)
#pragma unroll
    for (int jj = 0; jj < 4; ++jj) acc[ii][jj] = (f32x4){0.f, 0.f, 0.f, 0.f};
  float pm[4] = {-3.0e38f, -3.0e38f, -3.0e38f, -3.0e38f};

  auto STAGE = [&](int buf, int step) {
    const int sub = (step >= nt);
    const int ms = sub ? 256 : 0;
    const int k0 = (step - (sub ? nt : 0)) << 6;
    const int dh = k0 >> 7, e0 = k0 & 127;   // 64-col slab lies in one dh
#pragma unroll
    for (int ii = 0; ii < 4; ++ii) {
      const int c = tid + (ii << 9);         // 0..2047
      const int row = c >> 3, cs = c & 7;
      const int scs = cs ^ (row & 7);
      const int id = ids_s[ms + row + dh];   // lgkm read; keeps vmcnt pure
      gld_lds16(Eb + ((long)id << 7) + e0 + scs * 8, &As[buf][c * 8]);
      gld_lds16(Wc + (long)(N0 + row) * 640 + k0 + scs * 8, &Bs[buf][c * 8]);
    }
  };

  STAGE(0, 0);
  for (int t = 0; t < NS; ++t) {
    if (t + 1 < NS) {
      STAGE((t + 1) & 1, t + 1);
      asm volatile("s_waitcnt vmcnt(8)" ::: "memory");   // stage(t) done only
    } else {
      asm volatile("s_waitcnt vmcnt(0)" ::: "memory");
    }
    __builtin_amdgcn_s_barrier();          // A: stage(t) visible to all waves
    const short* Ab = As[t & 1];
    const short* Bb = Bs[t & 1];
#pragma unroll
    for (int ks = 0; ks < 2; ++ks) {
      const int csq = ks * 4 + (lane >> 4);
      short8 av[8], bv[4];
#pragma unroll
      for (int mf = 0; mf < 8; ++mf) {
        const int row = wr * 128 + mf * 16 + (lane & 15);
        av[mf] = *(const short8*)&Ab[row * 64 + (csq ^ (row & 7)) * 8];
      }
#pragma unroll
      for (int nf = 0; nf < 4; ++nf) {
        const int row = wc * 64 + nf * 16 + (lane & 15);
        bv[nf] = *(const short8*)&Bb[row * 64 + (csq ^ (row & 7)) * 8];
      }
#pragma unroll
      for (int mf = 0; mf < 8; ++mf)
#pragma unroll
        for (int nf = 0; nf < 4; ++nf)
          acc[mf][nf] = __builtin_amdgcn_mfma_f32_16x16x32_bf16(av[mf], bv[nf], acc[mf][nf], 0, 0, 0);
    }
    // Subtile-boundary fold: max is exactly associative; reset acc.
    if (t == nt - 1 || t == NS - 1) {
      const bool masked = (t == NS - 1);   // subtile 1: t_global = 256 + tloc
#pragma unroll
      for (int nf = 0; nf < 4; ++nf) {
#pragma unroll
        for (int mf = 0; mf < 8; ++mf) {
          const int tloc = wr * 128 + mf * 16 + (lane >> 4) * 4;
#pragma unroll
          for (int r = 0; r < 4; ++r) {
            if (!masked || (tloc + r <= 254 - nb))
              pm[nf] = fmaxf(pm[nf], acc[mf][nf][r]);
            acc[mf][nf][r] = 0.f;
          }
        }
      }
    }
    asm volatile("s_waitcnt lgkmcnt(0)" ::: "memory");
    __builtin_amdgcn_s_barrier();          // B: reads done before buf reuse
  }

  // Cross-wr combine in LDS, then bias+relu+store (no atomics).
#pragma unroll
  for (int nf = 0; nf < 4; ++nf) {
    float p = pm[nf];
    p = fmaxf(p, __shfl_xor(p, 16, 64));
    p = fmaxf(p, __shfl_xor(p, 32, 64));
    if ((lane >> 4) == 0) pm_s[wid][nf * 16 + (lane & 15)] = p;
  }
  __syncthreads();
  if (tid < 256) {
    const int wcx = tid >> 6, off = tid & 63;
    const int n = N0 + wcx * 64 + off;
    const float v0 = fmaxf(pm_s[wcx][off], pm_s[4 + wcx][off]);
    const float v = fmaxf(v0 + cb[n], 0.f);  // relu(max+bias) == max(relu)
    e_out[b * 1024 + n] = v;
    e_bf[b * 1024 + n] = __float2bfloat16(v);
  }
}

// ---------------------------------------------------------------------------
// 64x64-tile epilogue GEMM body, BK=256 (R19-verified). 4 waves 2x2, wave
// tile 32x32, 32-chunk involution swizzle, counted vmcnt(16).
template<int ACT, int OUTBF>
__device__ __forceinline__ void gemm256_body(const short* __restrict__ A, int lda,
                                             const short* __restrict__ W, int ldw,
                                             const float* __restrict__ bias,
                                             void* __restrict__ Cv, int ldc,
                                             int N, int K, int cofs, int M0, int N0,
                                             short* As0, short* As1,
                                             short* Bs0, short* Bs1) {
  const int tid = threadIdx.x, lane = tid & 63;
  const int wid = tid >> 6;
  const int wr = wid >> 1, wc = wid & 1;   // 2x2 wave grid; wave tile 32x32
  short* Asb[2] = {As0, As1};
  short* Bsb[2] = {Bs0, Bs1};

  f32x4 acc[2][2];
#pragma unroll
  for (int i = 0; i < 2; ++i)
#pragma unroll
    for (int j = 0; j < 2; ++j) acc[i][j] = (f32x4){0.f, 0.f, 0.f, 0.f};

  auto STAGE = [&](int buf, int k0) {
#pragma unroll
    for (int i = 0; i < 8; ++i) {          // A: 64 rows x 32 chunks = 2048
      const int c = tid + (i << 8);
      const int row = c >> 5, cs = c & 31;
      const int scs = cs ^ (row & 31);
      gld_lds16(A + (long)(M0 + row) * lda + k0 + scs * 8,
                &Asb[buf][row * 256 + cs * 8]);
    }
#pragma unroll
    for (int i = 0; i < 8; ++i) {          // B: 64 rows x 32 chunks = 2048
      const int c = tid + (i << 8);
      const int row = c >> 5, cs = c & 31;
      const int scs = cs ^ (row & 31);
      gld_lds16(W + (long)(N0 + row) * ldw + k0 + scs * 8,
                &Bsb[buf][row * 256 + cs * 8]);
    }
  };

  const int nt = K >> 8;                   // BK=256 steps
  STAGE(0, 0);
  for (int t = 0; t < nt; ++t) {
    if (t + 1 < nt) {
      STAGE((t + 1) & 1, (t + 1) << 8);
      asm volatile("s_waitcnt vmcnt(16)" ::: "memory");  // stage(t) done only
    } else {
      asm volatile("s_waitcnt vmcnt(0)" ::: "memory");
    }
    __builtin_amdgcn_s_barrier();
    const short* Ab = Asb[t & 1];
    const short* Bb = Bsb[t & 1];
#pragma unroll
    for (int ks = 0; ks < 8; ++ks) {       // 8 K-slices of 32
      const int csq = ks * 4 + (lane >> 4);
      short8 av[2], bv[2];
#pragma unroll
      for (int mf = 0; mf < 2; ++mf) {
        const int row = wr * 32 + mf * 16 + (lane & 15);
        av[mf] = *(const short8*)&Ab[row * 256 + (csq ^ (row & 31)) * 8];
      }
#pragma unroll
      for (int nf = 0; nf < 2; ++nf) {
        const int row = wc * 32 + nf * 16 + (lane & 15);
        bv[nf] = *(const short8*)&Bb[row * 256 + (csq ^ (row & 31)) * 8];
      }
#pragma unroll
      for (int mf = 0; mf < 2; ++mf)
#pragma unroll
        for (int nf = 0; nf < 2; ++nf)
          acc[mf][nf] = __builtin_amdgcn_mfma_f32_16x16x32_bf16(av[mf], bv[nf], acc[mf][nf], 0, 0, 0);
    }
    asm volatile("s_waitcnt lgkmcnt(0)" ::: "memory");
    __builtin_amdgcn_s_barrier();
  }

#pragma unroll
  for (int nf = 0; nf < 2; ++nf) {
    const int n = N0 + wc * 32 + nf * 16 + (lane & 15);
    const float bv = (n < N) ? bias[n] : 0.f;
#pragma unroll
    for (int mf = 0; mf < 2; ++mf) {
      const int m = M0 + wr * 32 + mf * 16 + (lane >> 4) * 4;
#pragma unroll
      for (int r = 0; r < 4; ++r) {
        float v = acc[mf][nf][r] + bv;
        if (ACT) v = tanhf(v);
        if (n < N) {
          if (OUTBF)
            ((__hip_bfloat16*)Cv)[(long)(m + r) * ldc + cofs + n] = __float2bfloat16(v);
          else
            ((float*)Cv)[(long)(m + r) * ldc + cofs + n] = v;
        }
      }
    }
  }
}

// ---------------------------------------------------------------------------
// 32x32-tile epilogue GEMM body, BK=512 (R20): K=2048 GEMMs in 4 serial
// steps. 4 waves 2x2, wave tile 16x16, LDS 2x(32x512) x2 = 128 KB, 64-chunk
// involution swizzle (cs^(row&31)), counted vmcnt(16). K order = ascending
// 32-element slices -> bit-identical.
template<int ACT, int OUTBF>
__device__ __forceinline__ void gemm512_body(const short* __restrict__ A, int lda,
                                             const short* __restrict__ W, int ldw,
                                             const float* __restrict__ bias,
                                             void* __restrict__ Cv, int ldc,
                                             int N, int K, int cofs, int M0, int N0,
                                             short* As0, short* As1,
                                             short* Bs0, short* Bs1) {
  const int tid = threadIdx.x, lane = tid & 63;
  const int wid = tid >> 6;
  const int wr = wid >> 1, wc = wid & 1;   // 2x2 wave grid; wave tile 16x16
  short* Asb[2] = {As0, As1};
  short* Bsb[2] = {Bs0, Bs1};

  f32x4 acc = (f32x4){0.f, 0.f, 0.f, 0.f};

  auto STAGE = [&](int buf, int k0) {
#pragma unroll
    for (int i = 0; i < 8; ++i) {          // A: 32 rows x 64 chunks = 2048
      const int c = tid + (i << 8);
      const int row = c >> 6, cs = c & 63;
      const int scs = cs ^ (row & 31);
      gld_lds16(A + (long)(M0 + row) * lda + k0 + scs * 8,
                &Asb[buf][row * 512 + cs * 8]);
    }
#pragma unroll
    for (int i = 0; i < 8; ++i) {          // B: 32 rows x 64 chunks = 2048
      const int c = tid + (i << 8);
      const int row = c >> 6, cs = c & 63;
      const int scs = cs ^ (row & 31);
      gld_lds16(W + (long)(N0 + row) * ldw + k0 + scs * 8,
                &Bsb[buf][row * 512 + cs * 8]);
    }
  };

  const int nt = K >> 9;                   // BK=512 steps
  STAGE(0, 0);
  for (int t = 0; t < nt; ++t) {
    if (t + 1 < nt) {
      STAGE((t + 1) & 1, (t + 1) << 9);
      asm volatile("s_waitcnt vmcnt(16)" ::: "memory");  // stage(t) done only
    } else {
      asm volatile("s_waitcnt vmcnt(0)" ::: "memory");
    }
    __builtin_amdgcn_s_barrier();
    const short* Ab = Asb[t & 1];
    const short* Bb = Bsb[t & 1];
#pragma unroll
    for (int ks = 0; ks < 16; ++ks) {      // 16 K-slices of 32
      const int csq = ks * 4 + (lane >> 4);
      const int arow = wr * 16 + (lane & 15);
      const int brow = wc * 16 + (lane & 15);
      short8 av = *(const short8*)&Ab[arow * 512 + (csq ^ (arow & 31)) * 8];
      short8 bv = *(const short8*)&Bb[brow * 512 + (csq ^ (brow & 31)) * 8];
      acc = __builtin_amdgcn_mfma_f32_16x16x32_bf16(av, bv, acc, 0, 0, 0);
    }
    asm volatile("s_waitcnt lgkmcnt(0)" ::: "memory");
    __builtin_amdgcn_s_barrier();
  }

  const int n = N0 + wc * 16 + (lane & 15);
  const float bv = (n < N) ? bias[n] : 0.f;
  const int m = M0 + wr * 16 + (lane >> 4) * 4;
#pragma unroll
  for (int r = 0; r < 4; ++r) {
    float v = acc[r] + bv;
    if (ACT) v = tanhf(v);
    if (n < N) {
      if (OUTBF)
        ((__hip_bfloat16*)Cv)[(long)(m + r) * ldc + cofs + n] = __float2bfloat16(v);
      else
        ((float*)Cv)[(long)(m + r) * ldc + cofs + n] = v;
    }
  }
}

template<int ACT, int OUTBF>
__global__ __launch_bounds__(256) void gemm256(const __hip_bfloat16* __restrict__ A_,
                                               int lda,
                                               const __hip_bfloat16* __restrict__ W_,
                                               int ldw,
                                               const float* __restrict__ bias,
                                               void* __restrict__ Cv, int ldc,
                                               int N, int K) {
  __shared__ __align__(16) short As[2][64 * 256];   // 64 KB
  __shared__ __align__(16) short Bs[2][64 * 256];   // 64 KB
  gemm256_body<ACT, OUTBF>((const short*)A_, lda, (const short*)W_, ldw, bias,
                           Cv, ldc, N, K, 0, blockIdx.y << 6, blockIdx.x << 6,
                           As[0], As[1], Bs[0], Bs[1]);
}

template<int ACT, int OUTBF>
__global__ __launch_bounds__(256) void gemm512(const __hip_bfloat16* __restrict__ A_,
                                               int lda,
                                               const __hip_bfloat16* __restrict__ W_,
                                               int ldw,
                                               const float* __restrict__ bias,
                                               void* __restrict__ Cv, int ldc,
                                               int N, int K) {
  __shared__ __align__(16) short As[2][32 * 512];   // 64 KB
  __shared__ __align__(16) short Bs[2][32 * 512];   // 64 KB
  gemm512_body<ACT, OUTBF>((const short*)A_, lda, (const short*)W_, ldw, bias,
                           Cv, ldc, N, K, 0, blockIdx.y << 5, blockIdx.x << 5,
                           As[0], As[1], Bs[0], Bs[1]);
}

// Fused u_sc (z=0: BK=256 body, K=1024, 64-col tiles, bx<16, by<4) +
// u_fic (z=1: BK=512 body, K=2048, 32-col tiles, bx<32, by<8) -> cat_sc_bf.
// Shared LDS: two 64 KB buffer pairs (both bodies use 32 KB per buffer).
__global__ __launch_bounds__(256) void gemm_sc_fic(
    const __hip_bfloat16* __restrict__ e_bf,
    const __hip_bfloat16* __restrict__ cat_mm_bf,
    const __hip_bfloat16* __restrict__ wt_sc,
    const __hip_bfloat16* __restrict__ wt_fic,
    const float* __restrict__ sc_b, const float* __restrict__ fic_b,
    __hip_bfloat16* __restrict__ cat_sc) {
  __shared__ __align__(16) short P[2][16384];       // 64 KB
  __shared__ __align__(16) short Q[2][16384];       // 64 KB
  const int z = blockIdx.z;
  if (z == 0) {
    if (blockIdx.x >= 16 || blockIdx.y >= 4) return;  // 16x4 tiles, 64x64
    gemm256_body<0, 1>((const short*)e_bf, 1024, (const short*)wt_sc, 1024,
                       sc_b, cat_sc, 2048, 1000, 1024, 0, blockIdx.y << 6,
                       blockIdx.x << 6, P[0], P[1], Q[0], Q[1]);
  } else {
    gemm512_body<1, 1>((const short*)cat_mm_bf, 2048, (const short*)wt_fic,
                       2048, fic_b, cat_sc, 2048, 1000, 2048, 1000,
                       blockIdx.y << 5, blockIdx.x << 5, P[0], P[1], Q[0], Q[1]);
  }
}

// ---------------------------------------------------------------------------
// Fused heads: per block b -- u_t (wave reduce), s1, then cat_mm_bf[b,:1000]=
// u_mm, [1000:2000]=u_mlp (s2 recomputed per api column), [2000:2048]=0.
__global__ __launch_bounds__(256) void k_heads(const float* __restrict__ e_buf,
                                               const float* __restrict__ W,
                                               const float* __restrict__ bias,
                                               const float* __restrict__ api,
                                               const float* __restrict__ mlp_w1,
                                               const float* __restrict__ mlp_b1,
                                               const float* __restrict__ mlp_w2,
                                               const float* __restrict__ mlp_b2,
                                               __hip_bfloat16* __restrict__ cat) {
  const int b = blockIdx.x, tid = threadIdx.x;
  float4 a = *(const float4*)(e_buf + b * 1024 + tid * 4);
  float acc[8];
#pragma unroll
  for (int f = 0; f < 8; ++f) {
    float4 w = *(const float4*)(W + f * 1024 + tid * 4);
    acc[f] = a.x * w.x + a.y * w.y + a.z * w.z + a.w * w.w;
  }
#pragma unroll
  for (int f = 0; f < 8; ++f)
    for (int off = 32; off; off >>= 1) acc[f] += __shfl_down(acc[f], off);
  __shared__ float red[4][8];
  __shared__ float ut_s[8];
  __shared__ float s1_s;
  if ((tid & 63) == 0) {
#pragma unroll
    for (int f = 0; f < 8; ++f) red[tid >> 6][f] = acc[f];
  }
  __syncthreads();
  if (tid == 0) {
    float s = 0.f;
#pragma unroll
    for (int f = 0; f < 8; ++f)
      ut_s[f] = red[0][f] + red[1][f] + red[2][f] + red[3][f] + bias[f];
#pragma unroll
    for (int f = 0; f < 8; ++f) {
      float t1 = 0.f;
#pragma unroll
      for (int fp = 0; fp < 8; ++fp) t1 += mlp_w1[f * 16 + fp] * ut_s[fp];
      s += t1 * mlp_w2[f];
    }
    s1_s = s;
  }
  __syncthreads();
  const float s1v = s1_s;
#pragma unroll
  for (int i = 0; i < 4; ++i) {
    const int j = tid + i * 256;           // 0..1023
    if (j < 1000) {
      float ap[8];
#pragma unroll
      for (int fp = 0; fp < 8; ++fp) ap[fp] = api[fp * 1000 + j];
      float umm = 0.f;
#pragma unroll
      for (int f = 0; f < 8; ++f) umm += ut_s[f] * ap[f];
      float s2 = mlp_b2[0];
#pragma unroll
      for (int f = 0; f < 8; ++f) {
        float t2 = mlp_b1[f];
#pragma unroll
        for (int fp = 0; fp < 8; ++fp) t2 += mlp_w1[f * 16 + 8 + fp] * ap[fp];
        s2 += t2 * mlp_w2[f];
      }
      cat[b * 2048 + j] = __float2bfloat16(umm);
      cat[b * 2048 + 1000 + j] = __float2bfloat16(tanhf(s1v + s2));
    }
  }
  if (tid < 48) cat[b * 2048 + 2000 + tid] = __float2bfloat16(0.f);
}

// ---------------------------------------------------------------------------
// FALLBACK (round-0 f32 path) — used only if ws_size is too small.
__global__ __launch_bounds__(256) void transpose_w(const float* __restrict__ w,
                                                   float* __restrict__ wt, int EH) {
  int idx = blockIdx.x * 256 + threadIdx.x;
  if (idx >= 256 * EH) return;
  int k = idx / EH, r = idx % EH;
  wt[r * 256 + k] = w[idx];
}

template<int H>
__global__ __launch_bounds__(256) void conv_pool(const int* __restrict__ ids,
                                                 const float* __restrict__ emb,
                                                 const float* __restrict__ wt,
                                                 const float* __restrict__ cbias,
                                                 float* __restrict__ e_out,
                                                 int hidx) {
  const int b = blockIdx.y;
  const int t0 = blockIdx.x * 32;
  const int L = 512 - H + 1;
  __shared__ float4 xs4[100][10];
  float* xs = (float*)xs4;
  const int tid = threadIdx.x;
  const int WIN = 32 + H - 1;
  for (int idx = tid; idx < WIN * 25; idx += 256) {
    int p = idx / 25, c = idx % 25;
    int s = t0 + p;
    float4 v = make_float4(0.f, 0.f, 0.f, 0.f);
    if (s < 512) {
      int id = ids[b * 512 + s];
      v = *(const float4*)(emb + (long)id * 100 + c * 4);
    }
    xs[(4 * c + 0) * 40 + p] = v.x;
    xs[(4 * c + 1) * 40 + p] = v.y;
    xs[(4 * c + 2) * 40 + p] = v.z;
    xs[(4 * c + 3) * 40 + p] = v.w;
  }
  __syncthreads();
  const int k = tid;
  float acc[32];
#pragma unroll
  for (int t = 0; t < 32; ++t) acc[t] = 0.f;
  const float* wk = wt + k;
  for (int e = 0; e < 100; ++e) {
    float win[36];
#pragma unroll
    for (int i = 0; i < 9; ++i)
      *(float4*)&win[i * 4] = *(const float4*)&xs[e * 40 + i * 4];
    float wr[H];
#pragma unroll
    for (int dh = 0; dh < H; ++dh) wr[dh] = wk[(e * H + dh) * 256];
#pragma unroll
    for (int t = 0; t < 32; ++t) {
      float s = acc[t];
#pragma unroll
      for (int dh = 0; dh < H; ++dh) s = fmaf(wr[dh], win[t + dh], s);
      acc[t] = s;
    }
  }
  const float bk = cbias[k];
  float m = 0.f;
#pragma unroll
  for (int t = 0; t < 32; ++t) {
    if (t0 + t < L) m = fmaxf(m, fmaxf(acc[t] + bk, 0.f));
  }
  atomicMax((int*)&e_out[b * 1024 + hidx * 256 + k], __float_as_int(m));
}

__global__ __launch_bounds__(256) void k_ut_s1(const float* __restrict__ e_buf,
                                               const float* __restrict__ W,
                                               const float* __restrict__ bias,
                                               const float* __restrict__ mlp_w1,
                                               const float* __restrict__ mlp_w2,
                                               float* __restrict__ u_t,
                                               float* __restrict__ s1) {
  const int b = blockIdx.x, tid = threadIdx.x;
  float4 a = *(const float4*)(e_buf + b * 1024 + tid * 4);
  float acc[8];
#pragma unroll
  for (int f = 0; f < 8; ++f) {
    float4 w = *(const float4*)(W + f * 1024 + tid * 4);
    acc[f] = a.x * w.x + a.y * w.y + a.z * w.z + a.w * w.w;
  }
#pragma unroll
  for (int f = 0; f < 8; ++f)
    for (int off = 32; off; off >>= 1) acc[f] += __shfl_down(acc[f], off);
  __shared__ float red[4][8];
  if ((tid & 63) == 0) {
#pragma unroll
    for (int f = 0; f < 8; ++f) red[tid >> 6][f] = acc[f];
  }
  __syncthreads();
  if (tid == 0) {
    float ut[8];
#pragma unroll
    for (int f = 0; f < 8; ++f) {
      ut[f] = red[0][f] + red[1][f] + red[2][f] + red[3][f] + bias[f];
      u_t[b * 8 + f] = ut[f];
    }
    float s = 0.f;
#pragma unroll
    for (int f = 0; f < 8; ++f) {
      float t1 = 0.f;
#pragma unroll
      for (int fp = 0; fp < 8; ++fp) t1 += mlp_w1[f * 16 + fp] * ut[fp];
      s += t1 * mlp_w2[f];
    }
    s1[b] = s;
  }
}

__global__ __launch_bounds__(256) void k_s2(const float* __restrict__ api,
                                            const float* __restrict__ mlp_w1,
                                            const float* __restrict__ mlp_b1,
                                            const float* __restrict__ mlp_w2,
                                            const float* __restrict__ mlp_b2,
                                            float* __restrict__ s2) {
  int a = blockIdx.x * 256 + threadIdx.x;
  if (a >= 1000) return;
  float ap[8];
#pragma unroll
  for (int fp = 0; fp < 8; ++fp) ap[fp] = api[fp * 1000 + a];
  float s = mlp_b2[0];
#pragma unroll
  for (int f = 0; f < 8; ++f) {
    float t2 = mlp_b1[f];
#pragma unroll
    for (int fp = 0; fp < 8; ++fp) t2 += mlp_w1[f * 16 + 8 + fp] * ap[fp];
    s += t2 * mlp_w2[f];
  }
  s2[a] = s;
}

__global__ __launch_bounds__(256) void k_cat_f32(const float* __restrict__ u_t,
                                                 const float* __restrict__ api,
                                                 const float* __restrict__ s1,
                                                 const float* __restrict__ s2,
                                                 float* __restrict__ cat_mm) {
  int j = blockIdx.x * 256 + threadIdx.x;
  int b = blockIdx.y;
  if (j >= 2000) return;
  if (j < 1000) {
    float v = 0.f;
#pragma unroll
    for (int f = 0; f < 8; ++f) v += u_t[b * 8 + f] * api[f * 1000 + j];
    cat_mm[b * 2000 + j] = v;
  } else {
    cat_mm[b * 2000 + j] = tanhf(s1[b] + s2[j - 1000]);
  }
}

template<int ACT>
__global__ __launch_bounds__(256) void gemm_tn(const float* __restrict__ A, int lda,
                                               const float* __restrict__ W, int ldw,
                                               const float* __restrict__ bias,
                                               float* __restrict__ C, int ldc,
                                               int M, int N, int K) {
  __shared__ float As[8][33];
  __shared__ float Ws[8][33];
  const int n0 = blockIdx.x * 32, m0 = blockIdx.y * 32;
  const int tid = threadIdx.x;
  const int tx = tid % 16, ty = tid / 16;
  const int ms = tid / 8, ks = tid % 8;
  float acc[2][2] = {{0.f, 0.f}, {0.f, 0.f}};
  for (int k0 = 0; k0 < K; k0 += 8) {
    As[ks][ms] = A[(m0 + ms) * lda + k0 + ks];
    int n = n0 + ms;
    Ws[ks][ms] = (n < N) ? W[n * ldw + k0 + ks] : 0.f;
    __syncthreads();
#pragma unroll
    for (int kk = 0; kk < 8; ++kk) {
      float a0 = As[kk][ty], a1 = As[kk][ty + 16];
      float w0 = Ws[kk][tx], w1 = Ws[kk][tx + 16];
      acc[0][0] = fmaf(a0, w0, acc[0][0]);
      acc[0][1] = fmaf(a0, w1, acc[0][1]);
      acc[1][0] = fmaf(a1, w0, acc[1][0]);
      acc[1][1] = fmaf(a1, w1, acc[1][1]);
    }
    __syncthreads();
  }
#pragma unroll
  for (int i = 0; i < 2; ++i)
#pragma unroll
    for (int j = 0; j < 2; ++j) {
      int m = m0 + ty + 16 * i, n = n0 + tx + 16 * j;
      if (n < N) {
        float v = acc[i][j] + bias[n];
        if (ACT) v = tanhf(v);
        C[m * ldc + n] = v;
      }
    }
}

// ---------------------------------------------------------------------------
extern "C" void kernel_launch(void* const* d_in, const int* in_sizes, int n_in,
                              void* d_out, int out_size, void* d_ws, size_t ws_size,
                              hipStream_t stream) {
  const int*   text_ids  = (const int*)d_in[0];
  const float* emb       = (const float*)d_in[1];
  const float* cw2       = (const float*)d_in[2];
  const float* cb2       = (const float*)d_in[3];
  const float* cw3       = (const float*)d_in[4];
  const float* cb3       = (const float*)d_in[5];
  const float* cw4       = (const float*)d_in[6];
  const float* cb4       = (const float*)d_in[7];
  const float* cw5       = (const float*)d_in[8];
  const float* cb5       = (const float*)d_in[9];
  const float* sc_w      = (const float*)d_in[10];
  const float* sc_b      = (const float*)d_in[11];
  const float* fic_fc_w  = (const float*)d_in[12];
  const float* fic_fc_b  = (const float*)d_in[13];
  const float* api       = (const float*)d_in[14];
  const float* mlp_w1    = (const float*)d_in[15];
  const float* mlp_b1    = (const float*)d_in[16];
  const float* mlp_w2    = (const float*)d_in[17];
  const float* mlp_b2    = (const float*)d_in[18];
  const float* fic_fcl_w = (const float*)d_in[19];
  const float* fic_fcl_b = (const float*)d_in[20];
  const float* fusion_w  = (const float*)d_in[21];
  const float* fusion_b  = (const float*)d_in[22];
  const float* out_w     = (const float*)d_in[23];
  const float* out_b     = (const float*)d_in[24];

  float* ws = (float*)d_ws;
  float* e_buf = ws;                       // 262144 f32
  float* cbias = e_buf + 262144;           // 1024
  // bf16 region (offset 263168*4 B, 16-aligned)
  __hip_bfloat16* bfb       = (__hip_bfloat16*)(cbias + 1024);
  __hip_bfloat16* e_bf      = bfb;                  // 262144 (256x1024)
  __hip_bfloat16* cat_mm_bf = e_bf + 262144;        // 524288 (256x2048)
  __hip_bfloat16* cat_sc_bf = cat_mm_bf + 524288;   // 524288 (256x2048)
  __hip_bfloat16* u_mmf_bf  = cat_sc_bf + 524288;   // 262144 (256x1024)
  __hip_bfloat16* emb_bf    = u_mmf_bf + 262144;    // 6400128 (50001x128)
  __hip_bfloat16* Wc        = emb_bf + 6400128;     // 655360
  __hip_bfloat16* wt_sc     = Wc + 655360;          // 1048576
  __hip_bfloat16* wt_fic    = wt_sc + 1048576;      // 2097152
  __hip_bfloat16* wt_fus    = wt_fic + 2097152;     // 2097152
  __hip_bfloat16* wt_out    = wt_fus + 2097152;     // 1048576
  int* ids_pad = (int*)(wt_out + 1048576);          // 131080 ints
  const size_t need_fast =
      263168UL * 4 + 14919808UL * 2 + 131080UL * 4;  // ~31.4 MB

  if (ws_size >= need_fast) {
    prep_all<<<4096, 256, 0, stream>>>(text_ids, emb, cw2, cw3, cw4, cw5,
                                       cb2, cb3, cb4, cb5, sc_w, fic_fcl_w,
                                       fusion_w, out_w, emb_bf, Wc, cbias,
                                       wt_sc, wt_fic, wt_fus, wt_out, ids_pad);
    conv_mfma<<<1024, 512, 0, stream>>>(emb_bf, ids_pad, Wc, cbias, e_buf, e_bf);
    k_heads<<<256, 256, 0, stream>>>(e_buf, fic_fc_w, fic_fc_b, api, mlp_w1,
                                     mlp_b1, mlp_w2, mlp_b2, cat_mm_bf);
    gemm_sc_fic<<<dim3(32, 8, 2), 256, 0, stream>>>(e_bf, cat_mm_bf, wt_sc,
                                                    wt_fic, sc_b, fic_fcl_b,
                                                    cat_sc_bf);
    gemm512<0, 1><<<dim3(32, 8), 256, 0, stream>>>(cat_sc_bf, 2048, wt_fus, 2048,
                                                   fusion_b, u_mmf_bf, 1024,
                                                   1000, 2048);
    gemm256<0, 0><<<dim3(16, 4), 256, 0, stream>>>(u_mmf_bf, 1024, wt_out, 1024,
                                                   out_b, d_out, 1000, 1000, 1024);
  } else {
    // f32 fallback (round-0 verified path) — needs zeroed e_buf for atomicMax
    hipMemsetAsync(e_buf, 0, 262144 * sizeof(float), stream);
    float* u_t    = (float*)bfb;            // 2048
    float* s1     = u_t + 2048;             // 256
    float* s2     = s1 + 256;               // 1024
    float* cat_mm = s2 + 1024;              // 512000
    float* cat_sc = cat_mm + 512000;        // 512000
    float* u_mmf  = cat_sc + 512000;        // 256000
    float* wt     = u_mmf + 256000;         // 358400
    transpose_w<<<200, 256, 0, stream>>>(cw2, wt + 0,      200);
    transpose_w<<<300, 256, 0, stream>>>(cw3, wt + 51200,  300);
    transpose_w<<<400, 256, 0, stream>>>(cw4, wt + 128000, 400);
    transpose_w<<<500, 256, 0, stream>>>(cw5, wt + 230400, 500);
    conv_pool<2><<<dim3(16, 256), 256, 0, stream>>>(text_ids, emb, wt + 0,      cb2, e_buf, 0);
    conv_pool<3><<<dim3(16, 256), 256, 0, stream>>>(text_ids, emb, wt + 51200,  cb3, e_buf, 1);
    conv_pool<4><<<dim3(16, 256), 256, 0, stream>>>(text_ids, emb, wt + 128000, cb4, e_buf, 2);
    conv_pool<5><<<dim3(16, 256), 256, 0, stream>>>(text_ids, emb, wt + 230400, cb5, e_buf, 3);
    k_ut_s1<<<256, 256, 0, stream>>>(e_buf, fic_fc_w, fic_fc_b, mlp_w1, mlp_w2, u_t, s1);
    k_s2<<<4, 256, 0, stream>>>(api, mlp_w1, mlp_b1, mlp_w2, mlp_b2, s2);
    k_cat_f32<<<dim3(8, 256), 256, 0, stream>>>(u_t, api, s1, s2, cat_mm);
    gemm_tn<0><<<dim3(32, 8), 256, 0, stream>>>(e_buf, 1024, sc_w, 1024, sc_b,
                                                cat_sc, 2000, 256, 1000, 1024);
    gemm_tn<1><<<dim3(32, 8), 256, 0, stream>>>(cat_mm, 2000, fic_fcl_w, 2000, fic_fcl_b,
                                                cat_sc + 1000, 2000, 256, 1000, 2000);
    gemm_tn<0><<<dim3(32, 8), 256, 0, stream>>>(cat_sc, 2000, fusion_w, 2000, fusion_b,
                                                u_mmf, 1000, 256, 1000, 2000);
    gemm_tn<0><<<dim3(32, 8), 256, 0, stream>>>(u_mmf, 1000, out_w, 1000, out_b,
                                                (float*)d_out, 1000, 256, 1000, 1000);
  }
}